// Round 13
// baseline (392.814 us; speedup 1.0000x reference)
//
#include <hip/hip_runtime.h>
#include <math.h>

#define DEV __device__ __forceinline__

DEV float sigm(float x){ return 1.f/(1.f+__expf(-x)); }
DEV float siluf(float x){ return x * sigm(x); }
DEV float softplusf(float x){ return x > 20.f ? x : log1pf(__expf(x)); }

static constexpr float NG = 131072.0f;   // group-norm element count per (b,g)
static constexpr float LOG2E = 1.4426950408889634f;

// ---- workspace layout (offsets in floats) ----
static constexpr size_t WS_H1    = 0;          // B*HW*128
static constexpr size_t WS_H1PRE = 1048576;    // h1pre; later yproj
static constexpr size_t WS_XC    = 2097152;    // spa xc; later spe xc2
static constexpr size_t WS_ZSIL  = 4194304;    // spa zsil
static constexpr size_t WS_XZD   = 6291456;    // dense xzd [8192][256] (2M); later spe zsil2
static constexpr size_t WS_QOFF  = 8388608;    // scan Q (2M); later proj2/logits (after scan2)
static constexpr size_t WS_LOG   = 8650752;    // logits (k_fusedw; Q/proj2 dead by then)
static constexpr size_t WS_Y     = 10485760;   // partPE; delta (aliases y); y; later epre
static constexpr size_t WS_POFF  = 12582912;   // scan P / hs (2M); after scan3: partials
static constexpr size_t WS_Y2    = 14155776;   // B*HW*128 (spe_cd; hs dead)
static constexpr size_t WS_PROJ  = 15204352;   // proj[8192][40]

// ---- in-kernel partial reduce: part[b*rowsPerB+row][8] -> dst16[16] ----
DEV void reduce_part(const float* __restrict__ part, int rowsPerB, float* dst16){
  int tid = threadIdx.x;
  int p = tid >> 4, sl = tid & 15;      // p = b*8 + j
  int b = p >> 3, j = p & 7;
  float s = 0.f;
  for (int row = sl; row < rowsPerB; row += 16)
    s += part[((size_t)b*rowsPerB + row)*8 + j];
  s += __shfl_xor(s,1); s += __shfl_xor(s,2);
  s += __shfl_xor(s,4); s += __shfl_xor(s,8);
  if (sl == 0) dst16[p] = s;
  __syncthreads();
}

// ---------------- pe 1x1 conv (tiled GEMM 32x64) + GN partials ---------------
__global__ void __launch_bounds__(256)
k_pe(const float* __restrict__ x, const float* __restrict__ pe_w,
     const float* __restrict__ pe_b, float* __restrict__ h1pre,
     float* __restrict__ part){
  __shared__ float As[16][36];
  __shared__ float Bs[16][64];
  __shared__ float red1[2][4], red2[2][4];
  int tid = threadIdx.x;
  int nx = blockIdx.x, my = blockIdx.y;
  int m0 = my*32, n0 = nx*64;
  int b = m0 >> 12, pl0 = m0 & 4095;
  int tx = tid & 15, ty = tid >> 4;
  float acc[2][4];
  #pragma unroll
  for (int i = 0; i < 2; i++)
    #pragma unroll
    for (int j = 0; j < 4; j++) acc[i][j] = 0.f;
  for (int k0 = 0; k0 < 128; k0 += 16){
    if (tid < 128){
      int k = tid >> 3, mm = (tid & 7)*4;
      float4 a = *(const float4*)(x + ((size_t)b*128 + k0+k)*4096 + pl0 + mm);
      *(float4*)&As[k][mm] = a;
    }
    {
      int n = tid >> 2, kq = (tid & 3)*4;
      float4 a = *(const float4*)(pe_w + (size_t)(n0+n)*128 + k0 + kq);
      Bs[kq+0][n] = a.x; Bs[kq+1][n] = a.y; Bs[kq+2][n] = a.z; Bs[kq+3][n] = a.w;
    }
    __syncthreads();
    #pragma unroll
    for (int k = 0; k < 16; k++){
      float2 av = *(const float2*)&As[k][ty*2];
      float4 bv = *(const float4*)&Bs[k][tx*4];
      acc[0][0] += av.x*bv.x; acc[0][1] += av.x*bv.y; acc[0][2] += av.x*bv.z; acc[0][3] += av.x*bv.w;
      acc[1][0] += av.y*bv.x; acc[1][1] += av.y*bv.y; acc[1][2] += av.y*bv.z; acc[1][3] += av.y*bv.w;
    }
    __syncthreads();
  }
  float4 bias = *(const float4*)(pe_b + n0 + tx*4);
  float s1 = 0.f, s2 = 0.f;
  #pragma unroll
  for (int i = 0; i < 2; i++){
    float4 st;
    st.x = acc[i][0]+bias.x; st.y = acc[i][1]+bias.y;
    st.z = acc[i][2]+bias.z; st.w = acc[i][3]+bias.w;
    s1 += st.x+st.y+st.z+st.w;
    s2 += st.x*st.x + st.y*st.y + st.z*st.z + st.w*st.w;
    *(float4*)(h1pre + (size_t)(m0 + ty*2 + i)*128 + n0 + tx*4) = st;
  }
  s1 += __shfl_xor(s1,1);  s2 += __shfl_xor(s2,1);
  s1 += __shfl_xor(s1,2);  s2 += __shfl_xor(s2,2);
  s1 += __shfl_xor(s1,4);  s2 += __shfl_xor(s2,4);
  s1 += __shfl_xor(s1,16); s2 += __shfl_xor(s2,16);
  s1 += __shfl_xor(s1,32); s2 += __shfl_xor(s2,32);
  int lane = tid & 63, w = tid >> 6;
  if ((lane & 55) == 0){
    int gl = (lane >> 3) & 1;
    red1[gl][w] = s1; red2[gl][w] = s2;
  }
  __syncthreads();
  if (tid < 8){
    int gg = tid >> 1, which = tid & 1;
    int gl = gg - nx*2;
    float v = 0.f;
    if (gl == 0 || gl == 1){
      v = which ? (red2[gl][0]+red2[gl][1]+red2[gl][2]+red2[gl][3])
                : (red1[gl][0]+red1[gl][1]+red1[gl][2]+red1[gl][3]);
    }
    int pblk = b*256 + (my & 127)*2 + nx;
    part[(size_t)pblk*8 + tid] = v;
  }
}

// ---------------- spa in-proj GEMM 64x64, inline pe-stats + GN+silu ----------
// grid dim3(8,128). Dense xzd output.
__global__ void __launch_bounds__(256)
k_xz(const float* __restrict__ h1pre, const float* __restrict__ in_w,
     const float* __restrict__ partPE, const float* __restrict__ gng,
     const float* __restrict__ gnb, float* __restrict__ h1,
     float* __restrict__ xzd, float* __restrict__ zsil){
  __shared__ float As[16][68];
  __shared__ float Bs[16][64];
  __shared__ float sst[16];
  reduce_part(partPE, 256, sst);
  int tid = threadIdx.x;
  int m0 = blockIdx.y*64, n0 = blockIdx.x*64;
  int tx = tid & 15, ty = tid >> 4;
  float acc[4][4];
  #pragma unroll
  for (int i = 0; i < 4; i++)
    #pragma unroll
    for (int j = 0; j < 4; j++) acc[i][j] = 0.f;
  for (int k0 = 0; k0 < 128; k0 += 16){
    {
      int m = tid >> 2, kk = (tid & 3)*4;
      int pixm = m0 + m, c0 = k0 + kk;
      int bb = pixm >> 12, g = c0 >> 5;
      float4 a = *(const float4*)(h1pre + (size_t)pixm*128 + c0);
      float mu = sst[bb*8 + g*2] * (1.f/NG);
      float var = sst[bb*8 + g*2 + 1] * (1.f/NG) - mu*mu;
      float rs = rsqrtf(var + 1e-5f);
      float4 gg = *(const float4*)(gng + c0);
      float4 gb = *(const float4*)(gnb + c0);
      float4 v;
      v.x = siluf((a.x-mu)*rs*gg.x + gb.x);
      v.y = siluf((a.y-mu)*rs*gg.y + gb.y);
      v.z = siluf((a.z-mu)*rs*gg.z + gb.z);
      v.w = siluf((a.w-mu)*rs*gg.w + gb.w);
      As[kk+0][m] = v.x; As[kk+1][m] = v.y; As[kk+2][m] = v.z; As[kk+3][m] = v.w;
      if (blockIdx.x == 0) *(float4*)(h1 + (size_t)pixm*128 + c0) = v;
    }
    {
      int n = tid >> 2, kq = (tid & 3)*4;
      float4 a = *(const float4*)(in_w + (size_t)(n0+n)*128 + k0 + kq);
      Bs[kq+0][n] = a.x; Bs[kq+1][n] = a.y; Bs[kq+2][n] = a.z; Bs[kq+3][n] = a.w;
    }
    __syncthreads();
    #pragma unroll
    for (int k = 0; k < 16; k++){
      float4 av = *(const float4*)&As[k][ty*4];
      float4 bv = *(const float4*)&Bs[k][tx*4];
      acc[0][0] += av.x*bv.x; acc[0][1] += av.x*bv.y; acc[0][2] += av.x*bv.z; acc[0][3] += av.x*bv.w;
      acc[1][0] += av.y*bv.x; acc[1][1] += av.y*bv.y; acc[1][2] += av.y*bv.z; acc[1][3] += av.y*bv.w;
      acc[2][0] += av.z*bv.x; acc[2][1] += av.z*bv.y; acc[2][2] += av.z*bv.z; acc[2][3] += av.z*bv.w;
      acc[3][0] += av.w*bv.x; acc[3][1] += av.w*bv.y; acc[3][2] += av.w*bv.z; acc[3][3] += av.w*bv.w;
    }
    __syncthreads();
  }
  if (n0 < 256){
    #pragma unroll
    for (int i = 0; i < 4; i++){
      float4 st; st.x = acc[i][0]; st.y = acc[i][1]; st.z = acc[i][2]; st.w = acc[i][3];
      *(float4*)(xzd + (size_t)(m0 + ty*4 + i)*256 + n0 + tx*4) = st;
    }
  } else {
    #pragma unroll
    for (int i = 0; i < 4; i++){
      float4 st;
      st.x = siluf(acc[i][0]); st.y = siluf(acc[i][1]);
      st.z = siluf(acc[i][2]); st.w = siluf(acc[i][3]);
      *(float4*)(zsil + (size_t)(m0 + ty*4 + i)*256 + (n0-256) + tx*4) = st;
    }
  }
}

// ---------------- fused conv + x-proj + delta + scan1 ----------------
// grid 512; block = 16 tokens = one scan chunk (bc = blockIdx.x).
__global__ void __launch_bounds__(256)
k_projc(const float* __restrict__ xzd, const float* __restrict__ cw,
        const float* __restrict__ cb, const float* __restrict__ xpw,
        const float* __restrict__ dtw, const float* __restrict__ dtb,
        const float* __restrict__ Alog,
        float* __restrict__ xc, float* __restrict__ proj,
        float* __restrict__ delta, float* __restrict__ P,
        float* __restrict__ Q){
  __shared__ float xct[16*260];
  __shared__ float s_pr[16][40];
  int tid = threadIdx.x;
  int bc = blockIdx.x;
  int m0 = bc * 16;
  // phase A: depthwise conv K=4 + silu
  {
    int slot = tid >> 6, lane = tid & 63;
    int d4 = lane*4;
    float4 cbv = *(const float4*)(cb + d4);
    float4 cw0 = *(const float4*)(cw + (size_t)(d4+0)*4);
    float4 cw1 = *(const float4*)(cw + (size_t)(d4+1)*4);
    float4 cw2 = *(const float4*)(cw + (size_t)(d4+2)*4);
    float4 cw3 = *(const float4*)(cw + (size_t)(d4+3)*4);
    const float* c0p = (const float*)&cw0;
    const float* c1p = (const float*)&cw1;
    const float* c2p = (const float*)&cw2;
    const float* c3p = (const float*)&cw3;
    for (int i = 0; i < 4; i++){
      int t = slot*4 + i;
      int tok = m0 + t;
      int l = tok & 4095;
      float4 acc = cbv;
      #pragma unroll
      for (int k = 0; k < 4; k++){
        int ls = l - 3 + k;
        if (ls >= 0){
          float4 xv = *(const float4*)(xzd + (size_t)(tok-3+k)*256 + d4);
          acc.x += xv.x * c0p[k];
          acc.y += xv.y * c1p[k];
          acc.z += xv.z * c2p[k];
          acc.w += xv.w * c3p[k];
        }
      }
      float4 s;
      s.x = siluf(acc.x); s.y = siluf(acc.y); s.z = siluf(acc.z); s.w = siluf(acc.w);
      *(float4*)&xct[t*260 + d4] = s;
      *(float4*)(xc + (size_t)tok*256 + d4) = s;
    }
  }
  __syncthreads();
  // phase B: x-proj -> s_pr + proj global
  {
    int t = tid & 15, jq = tid >> 4;
    int tok = m0 + t;
    float a0 = 0.f, a1 = 0.f, a2 = 0.f;
    for (int k0 = 0; k0 < 256; k0 += 4){
      float4 av = *(const float4*)&xct[t*260 + k0];
      float4 w0 = *(const float4*)(xpw + (size_t)jq*256 + k0);
      float4 w1 = *(const float4*)(xpw + (size_t)(jq+16)*256 + k0);
      a0 += av.x*w0.x + av.y*w0.y + av.z*w0.z + av.w*w0.w;
      a1 += av.x*w1.x + av.y*w1.y + av.z*w1.z + av.w*w1.w;
      if (jq < 8){
        float4 w2 = *(const float4*)(xpw + (size_t)(jq+32)*256 + k0);
        a2 += av.x*w2.x + av.y*w2.y + av.z*w2.z + av.w*w2.w;
      }
    }
    float* pr = proj + (size_t)tok*40;
    pr[jq] = a0;      s_pr[t][jq] = a0;
    pr[jq+16] = a1;   s_pr[t][jq+16] = a1;
    if (jq < 8){ pr[jq+32] = a2; s_pr[t][jq+32] = a2; }
  }
  __syncthreads();
  // phase C: delta + chunk scan (thread = d; n in regs)
  {
    int d = tid;
    const float4* wr = (const float4*)(dtw + (size_t)d*8);
    float4 w0 = wr[0], w1 = wr[1];
    float bd = dtb[d];
    float An[16];
    {
      const float4* ar = (const float4*)(Alog + (size_t)d*16);
      #pragma unroll
      for (int k = 0; k < 4; k++){
        float4 a = ar[k];
        An[k*4]   = -__expf(a.x)*LOG2E; An[k*4+1] = -__expf(a.y)*LOG2E;
        An[k*4+2] = -__expf(a.z)*LOG2E; An[k*4+3] = -__expf(a.w)*LOG2E;
      }
    }
    float Pv[16], Qv[16];
    #pragma unroll
    for (int n = 0; n < 16; n++){ Pv[n] = 1.f; Qv[n] = 0.f; }
    for (int t = 0; t < 16; t++){
      float dv = bd + s_pr[t][0]*w0.x + s_pr[t][1]*w0.y + s_pr[t][2]*w0.z + s_pr[t][3]*w0.w
                    + s_pr[t][4]*w1.x + s_pr[t][5]*w1.y + s_pr[t][6]*w1.z + s_pr[t][7]*w1.w;
      dv = softplusf(dv);
      delta[(size_t)(m0+t)*256 + d] = dv;
      float xv = xct[t*260 + d];
      float dBx = dv*xv;
      #pragma unroll
      for (int n = 0; n < 16; n++){
        float a = exp2f(dv*An[n]);
        Qv[n] = a*Qv[n] + s_pr[t][8+n]*dBx;
        Pv[n] *= a;
      }
    }
    float* Pp = P + (size_t)bc*4096 + d*16;
    float* Qp = Q + (size_t)bc*4096 + d*16;
    #pragma unroll
    for (int k = 0; k < 4; k++){
      float4 pv; pv.x=Pv[k*4]; pv.y=Pv[k*4+1]; pv.z=Pv[k*4+2]; pv.w=Pv[k*4+3];
      float4 qv; qv.x=Qv[k*4]; qv.y=Qv[k*4+1]; qv.z=Qv[k*4+2]; qv.w=Qv[k*4+3];
      *(float4*)(Pp + k*4) = pv;
      *(float4*)(Qp + k*4) = qv;
    }
  }
}

// ---------------- scan phase 2: 256-chunk scan; lane owns 4 chunks -----------
__global__ void __launch_bounds__(256)
k_scan2(const float* __restrict__ P, const float* __restrict__ Q,
        float* __restrict__ hs){
  __shared__ float Ps[256][17], Qs[256][17];
  int tid = threadIdx.x;
  int b = blockIdx.x >> 8;
  int dn0 = (blockIdx.x & 255) * 16;
  for (int i = tid; i < 1024; i += 256){
    int ch = i >> 2, g = (i & 3)*4;
    size_t gaddr = (size_t)(b*256+ch)*4096 + dn0 + g;
    float4 p = *(const float4*)(P + gaddr);
    float4 q = *(const float4*)(Q + gaddr);
    Ps[ch][g]=p.x; Ps[ch][g+1]=p.y; Ps[ch][g+2]=p.z; Ps[ch][g+3]=p.w;
    Qs[ch][g]=q.x; Qs[ch][g+1]=q.y; Qs[ch][g+2]=q.z; Qs[ch][g+3]=q.w;
  }
  __syncthreads();
  int lane = tid & 63, wv = tid >> 6;
  for (int rep = 0; rep < 4; rep++){
    int c = wv*4 + rep;
    float p0 = Ps[4*lane+0][c], q0 = Qs[4*lane+0][c];
    float p1 = Ps[4*lane+1][c], q1 = Qs[4*lane+1][c];
    float p2 = Ps[4*lane+2][c], q2 = Qs[4*lane+2][c];
    float p3 = Ps[4*lane+3][c], q3 = Qs[4*lane+3][c];
    float p = p0, q = q0;
    q = p1*q + q1; p *= p1;
    q = p2*q + q2; p *= p2;
    q = p3*q + q3; p *= p3;
    #pragma unroll
    for (int off = 1; off < 64; off <<= 1){
      float pp = __shfl_up(p, off);
      float qp = __shfl_up(q, off);
      if (lane >= off){ q = p*qp + q; p = p*pp; }
    }
    float h0 = __shfl_up(q, 1);
    if (lane == 0) h0 = 0.f;
    float h1 = p0*h0 + q0;
    float h2 = p1*h1 + q1;
    float h3 = p2*h2 + q2;
    Ps[4*lane+0][c] = h0;
    Ps[4*lane+1][c] = h1;
    Ps[4*lane+2][c] = h2;
    Ps[4*lane+3][c] = h3;
  }
  __syncthreads();
  for (int i = tid; i < 1024; i += 256){
    int ch = i >> 2, g = (i & 3)*4;
    size_t gaddr = (size_t)(b*256+ch)*4096 + dn0 + g;
    float4 h;
    h.x = Ps[ch][g]; h.y = Ps[ch][g+1]; h.z = Ps[ch][g+2]; h.w = Ps[ch][g+3];
    *(float4*)(hs + gaddr) = h;
  }
}

// ---------------- scan phase 3: replay + y; thread=(d, n-quartet) ------------
__global__ void __launch_bounds__(256)
k_scan3(const float* __restrict__ delta, const float* __restrict__ proj,
        const float* __restrict__ xc, const float* __restrict__ zsil,
        const float* __restrict__ Alog, const float* __restrict__ Dv,
        const float* __restrict__ hs, float* __restrict__ y){
  int blk = blockIdx.x;
  int dblk = blk & 3;
  int bc = blk >> 2;
  int b = bc >> 8, chunk = bc & 255;
  int tid = threadIdx.x;
  int dl = tid >> 2, ng = tid & 3;
  int d = dblk*64 + dl;
  float4 a4 = *(const float4*)(Alog + (size_t)d*16 + ng*4);
  float An[4] = {-__expf(a4.x)*LOG2E, -__expf(a4.y)*LOG2E,
                 -__expf(a4.z)*LOG2E, -__expf(a4.w)*LOG2E};
  float Dd = Dv[d];
  float h[4];
  {
    size_t o = (size_t)bc*4096 + dblk*1024 + tid*4;
    float4 hv = *(const float4*)(hs + o);
    h[0]=hv.x; h[1]=hv.y; h[2]=hv.z; h[3]=hv.w;
  }
  size_t row0 = (size_t)(b*4096 + chunk*16);
  for (int l = 0; l < 16; l++){
    size_t r = row0 + l;
    float dv = delta[r*256 + d];
    float xv = xc[r*256 + d];
    float4 bm = *(const float4*)(proj + r*40 + 8 + ng*4);
    float4 cm = *(const float4*)(proj + r*40 + 24 + ng*4);
    float dBx = dv*xv;
    float bmv[4] = {bm.x, bm.y, bm.z, bm.w};
    float cmv[4] = {cm.x, cm.y, cm.z, cm.w};
    float ys = 0.f;
    #pragma unroll
    for (int k = 0; k < 4; k++){
      float a = exp2f(dv*An[k]);
      h[k] = a*h[k] + bmv[k]*dBx;
      ys += h[k]*cmv[k];
    }
    ys += __shfl_xor(ys, 1);
    ys += __shfl_xor(ys, 2);
    if (ng == 0){
      float zv = zsil[r*256 + d];
      y[r*256 + d] = (ys + Dd*xv) * zv;
    }
  }
}

// ---------------- spa out-proj: tiled GEMM 32x64 + GN partials ---------------
__global__ void __launch_bounds__(256)
k_outproj(const float* __restrict__ y, const float* __restrict__ out_w,
          float* __restrict__ yproj, float* __restrict__ part){
  __shared__ float As[16][36];
  __shared__ float Bs[16][64];
  __shared__ float red1[2][4], red2[2][4];
  int tid = threadIdx.x;
  int nx = blockIdx.x, my = blockIdx.y;
  int m0 = my*32, n0 = nx*64;
  int b = m0 >> 12;
  int tx = tid & 15, ty = tid >> 4;
  float acc[2][4];
  #pragma unroll
  for (int i = 0; i < 2; i++)
    #pragma unroll
    for (int j = 0; j < 4; j++) acc[i][j] = 0.f;
  for (int k0 = 0; k0 < 256; k0 += 16){
    if (tid < 128){
      int m = tid >> 2, kk = (tid & 3)*4;
      float4 a = *(const float4*)(y + (size_t)(m0+m)*256 + k0+kk);
      As[kk+0][m] = a.x; As[kk+1][m] = a.y; As[kk+2][m] = a.z; As[kk+3][m] = a.w;
    }
    {
      int n = tid >> 2, kq = (tid & 3)*4;
      float4 a = *(const float4*)(out_w + (size_t)(n0+n)*256 + k0 + kq);
      Bs[kq+0][n] = a.x; Bs[kq+1][n] = a.y; Bs[kq+2][n] = a.z; Bs[kq+3][n] = a.w;
    }
    __syncthreads();
    #pragma unroll
    for (int k = 0; k < 16; k++){
      float2 av = *(const float2*)&As[k][ty*2];
      float4 bv = *(const float4*)&Bs[k][tx*4];
      acc[0][0] += av.x*bv.x; acc[0][1] += av.x*bv.y; acc[0][2] += av.x*bv.z; acc[0][3] += av.x*bv.w;
      acc[1][0] += av.y*bv.x; acc[1][1] += av.y*bv.y; acc[1][2] += av.y*bv.z; acc[1][3] += av.y*bv.w;
    }
    __syncthreads();
  }
  float s1 = 0.f, s2 = 0.f;
  #pragma unroll
  for (int i = 0; i < 2; i++){
    float4 st; st.x = acc[i][0]; st.y = acc[i][1]; st.z = acc[i][2]; st.w = acc[i][3];
    s1 += st.x+st.y+st.z+st.w;
    s2 += st.x*st.x + st.y*st.y + st.z*st.z + st.w*st.w;
    *(float4*)(yproj + (size_t)(m0 + ty*2 + i)*128 + n0 + tx*4) = st;
  }
  s1 += __shfl_xor(s1,1);  s2 += __shfl_xor(s2,1);
  s1 += __shfl_xor(s1,2);  s2 += __shfl_xor(s2,2);
  s1 += __shfl_xor(s1,4);  s2 += __shfl_xor(s2,4);
  s1 += __shfl_xor(s1,16); s2 += __shfl_xor(s2,16);
  s1 += __shfl_xor(s1,32); s2 += __shfl_xor(s2,32);
  int lane = tid & 63, w = tid >> 6;
  if ((lane & 55) == 0){
    int gl = (lane >> 3) & 1;
    red1[gl][w] = s1; red2[gl][w] = s2;
  }
  __syncthreads();
  if (tid < 8){
    int gg = tid >> 1, which = tid & 1;
    int gl = gg - nx*2;
    float v = 0.f;
    if (gl == 0 || gl == 1){
      v = which ? (red2[gl][0]+red2[gl][1]+red2[gl][2]+red2[gl][3])
                : (red1[gl][0]+red1[gl][1]+red1[gl][2]+red1[gl][3]);
    }
    int pblk = b*256 + (my & 127)*2 + nx;
    part[(size_t)pblk*8 + tid] = v;
  }
}

// ---------------- spe A+B: in-proj + conv + silu + x-proj --------------------
__global__ void __launch_bounds__(256)
k_spe_ab(const float* __restrict__ h1, const float* __restrict__ in_w,
         const float* __restrict__ conv_w, const float* __restrict__ conv_b,
         const float* __restrict__ xpw, float* __restrict__ xc2,
         float* __restrict__ zsil2, float* __restrict__ proj2){
  __shared__ float s_in[4][128];
  __shared__ float s_xc[64][66];
  int tid = threadIdx.x;
  int w = tid >> 6, lane = tid & 63;
  {
    float wx[32], wz[32];
    const float4* rx = (const float4*)(in_w + (size_t)lane*32);
    const float4* rz = (const float4*)(in_w + (size_t)(64+lane)*32);
    #pragma unroll
    for (int k = 0; k < 8; k++){
      float4 a = rx[k]; wx[k*4]=a.x; wx[k*4+1]=a.y; wx[k*4+2]=a.z; wx[k*4+3]=a.w;
      float4 b = rz[k]; wz[k*4]=b.x; wz[k*4+1]=b.y; wz[k*4+2]=b.z; wz[k*4+3]=b.w;
    }
    float4 cwv = ((const float4*)conv_w)[lane];
    float cbv = conv_b[lane];
    for (int i = 0; i < 4; i++){
      int pix = blockIdx.x*16 + w*4 + i;
      float2 hv = ((const float2*)(h1 + (size_t)pix*128))[lane];
      s_in[w][2*lane] = hv.x; s_in[w][2*lane+1] = hv.y;
      float xpr[4], zs[4];
      #pragma unroll
      for (int l = 0; l < 4; l++){
        const float4* sv = (const float4*)&s_in[w][l*32];
        float ax = 0.f, az = 0.f;
        #pragma unroll
        for (int c4 = 0; c4 < 8; c4++){
          float4 v = sv[c4];
          ax += v.x*wx[c4*4] + v.y*wx[c4*4+1] + v.z*wx[c4*4+2] + v.w*wx[c4*4+3];
          az += v.x*wz[c4*4] + v.y*wz[c4*4+1] + v.z*wz[c4*4+2] + v.w*wz[c4*4+3];
        }
        xpr[l] = ax; zs[l] = siluf(az);
      }
      #pragma unroll
      for (int l = 0; l < 4; l++){
        float v = cbv;
        if (l >= 3) v += xpr[l-3]*cwv.x;
        if (l >= 2) v += xpr[l-2]*cwv.y;
        if (l >= 1) v += xpr[l-1]*cwv.z;
        v += xpr[l]*cwv.w;
        float sx = siluf(v);
        int t = (w*4+i)*4 + l;
        int tok = blockIdx.x*64 + t;
        s_xc[t][lane] = sx;
        xc2 [(size_t)tok*64 + lane] = sx;
        zsil2[(size_t)tok*64 + lane] = zs[l];
      }
    }
  }
  __syncthreads();
  {
    int t = lane;
    float a[9];
    #pragma unroll
    for (int j = 0; j < 9; j++) a[j] = 0.f;
    for (int k = 0; k < 64; k++){
      float xk = s_xc[t][k];
      #pragma unroll
      for (int j = 0; j < 9; j++){
        int ja = w*9 + j; if (ja > 33) ja = 33;
        a[j] += xk * xpw[(size_t)ja*64 + k];
      }
    }
    float* pr = proj2 + (size_t)(blockIdx.x*64 + t)*36;
    #pragma unroll
    for (int j = 0; j < 9; j++){
      int ja = w*9 + j;
      if (ja < 34) pr[ja] = a[j];
    }
  }
}

// ---------------- spe C+D: scan + gate -> LDS -> out-proj + GN partials ------
__global__ void __launch_bounds__(256)
k_spe_cd(const float* __restrict__ xc2, const float* __restrict__ zsil2,
         const float* __restrict__ proj, const float* __restrict__ dt_w,
         const float* __restrict__ dt_b, const float* __restrict__ Alog,
         const float* __restrict__ Dvec, const float* __restrict__ out_w,
         float* __restrict__ y2, float* __restrict__ part){
  __shared__ float s_y[64][68];
  __shared__ float ldsWT[64*32];
  __shared__ float bst[8];
  int tid = threadIdx.x;
  int w = tid >> 6, lane = tid & 63;
  for (int i = tid; i < 2048; i += 256){
    int c2 = i >> 6, dd = i & 63;
    ldsWT[dd*32 + c2] = out_w[i];
  }
  if (tid < 8) bst[tid] = 0.f;
  // phase C
  {
    float2 dtwv = ((const float2*)dt_w)[lane];
    float dbv = dt_b[lane], Dd = Dvec[lane];
    float An[16];
    const float4* ar = (const float4*)(Alog + (size_t)lane*16);
    #pragma unroll
    for (int k = 0; k < 4; k++){
      float4 a = ar[k];
      An[k*4]   = -__expf(a.x)*LOG2E; An[k*4+1] = -__expf(a.y)*LOG2E;
      An[k*4+2] = -__expf(a.z)*LOG2E; An[k*4+3] = -__expf(a.w)*LOG2E;
    }
    for (int i = 0; i < 4; i++){
      int pix = blockIdx.x*16 + w*4 + i;
      float h[16];
      #pragma unroll
      for (int n = 0; n < 16; n++) h[n] = 0.f;
      #pragma unroll
      for (int l = 0; l < 4; l++){
        int tok = pix*4 + l;
        float pj[36];
        {
          const float4* pr = (const float4*)(proj + (size_t)tok*36);
          #pragma unroll
          for (int k = 0; k < 9; k++){
            float4 v = pr[k];
            pj[k*4]=v.x; pj[k*4+1]=v.y; pj[k*4+2]=v.z; pj[k*4+3]=v.w;
          }
        }
        float xv = xc2[(size_t)tok*64 + lane];
        float zv = zsil2[(size_t)tok*64 + lane];
        float dt = softplusf(dbv + pj[0]*dtwv.x + pj[1]*dtwv.y);
        float ys = 0.f;
        #pragma unroll
        for (int n = 0; n < 16; n++){
          float a = exp2f(dt * An[n]);
          h[n] = a*h[n] + dt * pj[2+n] * xv;
          ys += h[n] * pj[18+n];
        }
        s_y[(w*4+i)*4 + l][lane] = (ys + Dd*xv) * zv;
      }
    }
  }
  __syncthreads();
  // phase D
  {
    int c2 = lane & 31, slot = lane >> 5;
    int tl0 = w*16 + slot;
    float acc[8];
    #pragma unroll
    for (int i = 0; i < 8; i++) acc[i] = 0.f;
    for (int dd4 = 0; dd4 < 16; dd4++){
      float w0 = ldsWT[(dd4*4+0)*32 + c2];
      float w1 = ldsWT[(dd4*4+1)*32 + c2];
      float w2 = ldsWT[(dd4*4+2)*32 + c2];
      float w3 = ldsWT[(dd4*4+3)*32 + c2];
      #pragma unroll
      for (int i = 0; i < 8; i++){
        int t = tl0 + 2*i;
        float4 yv = *(const float4*)&s_y[t][dd4*4];
        acc[i] += yv.x*w0 + yv.y*w1 + yv.z*w2 + yv.w*w3;
      }
    }
    #pragma unroll
    for (int i = 0; i < 8; i++){
      int tok = blockIdx.x*64 + tl0 + 2*i;
      int pix = tok >> 2, l = tok & 3;
      y2[(size_t)pix*128 + l*32 + c2] = acc[i];
      float s1 = acc[i], s2 = acc[i]*acc[i];
      s1 += __shfl_xor(s1,1);  s2 += __shfl_xor(s2,1);
      s1 += __shfl_xor(s1,2);  s2 += __shfl_xor(s2,2);
      s1 += __shfl_xor(s1,4);  s2 += __shfl_xor(s2,4);
      s1 += __shfl_xor(s1,8);  s2 += __shfl_xor(s2,8);
      s1 += __shfl_xor(s1,16); s2 += __shfl_xor(s2,16);
      if (c2 == 0){
        atomicAdd(&bst[l*2+0], s1);
        atomicAdd(&bst[l*2+1], s2);
      }
    }
  }
  __syncthreads();
  if (tid < 8) part[(size_t)blockIdx.x*8 + tid] = bst[tid];
}

// ---------------- fused fuse + dw: feat in LDS, logits + conv + GN partials --
// grid 256 = 2b x 16ty x 8tx; interior 4x8 pixels, halo 6x10.
__global__ void __launch_bounds__(256)
k_fusedw(const float* __restrict__ h1, const float* __restrict__ yproj,
         const float* __restrict__ y2, const float* __restrict__ partSPA,
         const float* __restrict__ partSPE,
         const float* __restrict__ spa_g, const float* __restrict__ spa_b,
         const float* __restrict__ spe_g, const float* __restrict__ spe_b,
         const float* __restrict__ fuse_w, const float* __restrict__ cls_w,
         const float* __restrict__ cls_b, const float* __restrict__ dww,
         float* __restrict__ logits, float* __restrict__ epre,
         float* __restrict__ part){
  __shared__ float ft[60*129];
  __shared__ float clsL[10*129];
  __shared__ float sst[32];
  __shared__ float red1[4][64], red2[4][64];
  int tid = threadIdx.x;
  reduce_part(partSPA, 256, sst);
  reduce_part(partSPE, 256, sst+16);
  for (int i = tid; i < 1280; i += 256){
    int o = i >> 7, cc = i & 127;
    clsL[o*129 + cc] = cls_w[o*128 + cc];
  }
  int blk = blockIdx.x;
  int b = blk >> 7, rem = blk & 127;
  int ty = rem >> 3, tx = rem & 7;
  int r0 = ty*4, c0 = tx*8;
  float e0 = __expf(fuse_w[0]), e1 = __expf(fuse_w[1]);
  float wA = e0/(e0+e1), wB = e1/(e0+e1);
  for (int idx = tid; idx < 7680; idx += 256){
    int pos = idx >> 7, c = idx & 127;
    int hr = pos/10, hc = pos - hr*10;
    int ry = r0 + hr - 1, rx = c0 + hc - 1;
    float f = 0.f;
    if (ry >= 0 && ry < 64 && rx >= 0 && rx < 64){
      size_t pix = (size_t)((b<<12)|(ry<<6)|rx);
      int g = c >> 5;
      float m1 = sst[b*8 + g*2]      * (1.f/NG);
      float v1 = sst[b*8 + g*2 + 1]  * (1.f/NG) - m1*m1;
      float m2 = sst[16 + b*8 + g*2] * (1.f/NG);
      float v2 = sst[16 + b*8 + g*2+1]*(1.f/NG) - m2*m2;
      float h = h1[pix*128 + c];
      float sa = siluf((yproj[pix*128+c]-m1)*rsqrtf(v1+1e-5f)*spa_g[c] + spa_b[c]) + h;
      float sp = h + siluf((y2[pix*128+c]-m2)*rsqrtf(v2+1e-5f)*spe_g[c] + spe_b[c]);
      f = sa*wA + sp*wB + h;
    }
    ft[pos*129 + c] = f;
  }
  __syncthreads();
  // conv 3x3 over interior + stats
  int c = tid & 127, pl = tid >> 7;
  float w9[9];
  #pragma unroll
  for (int k = 0; k < 9; k++) w9[k] = dww[c*9+k];
  float s1 = 0.f, s2 = 0.f;
  for (int i = 0; i < 16; i++){
    int px = i*2 + pl;
    int py = px >> 3, pxx = px & 7;
    float acc = 0.f;
    #pragma unroll
    for (int dy = 0; dy < 3; dy++)
      #pragma unroll
      for (int dx = 0; dx < 3; dx++)
        acc += ft[((py+dy)*10 + (pxx+dx))*129 + c] * w9[dy*3+dx];
    epre[(size_t)((b<<12)|((r0+py)<<6)|(c0+pxx))*128 + c] = acc;
    s1 += acc; s2 += acc*acc;
  }
  // logits for interior pixels
  for (int idx = tid; idx < 320; idx += 256){
    int px = idx/10, o = idx - px*10;
    int py = px >> 3, pxx = px & 7;
    int pos = (py+1)*10 + (pxx+1);
    float acc = cls_b[o];
    for (int cc = 0; cc < 128; cc++)
      acc += ft[pos*129 + cc] * clsL[o*129 + cc];
    logits[(size_t)((b<<12)|((r0+py)<<6)|(c0+pxx))*16 + o] = acc;
  }
  // block GN partials
  int g = c >> 5;
  int ridx0 = (c & 31) | (pl << 5);
  red1[g][ridx0] = s1; red2[g][ridx0] = s2;
  __syncthreads();
  int rg = tid >> 6, ridx = tid & 63;
  for (int s = 32; s >= 1; s >>= 1){
    if (ridx < s){ red1[rg][ridx] += red1[rg][ridx+s]; red2[rg][ridx] += red2[rg][ridx+s]; }
    __syncthreads();
  }
  if (ridx == 0){
    part[(size_t)blk*8 + rg*2+0] = red1[rg][0];
    part[(size_t)blk*8 + rg*2+1] = red2[rg][0];
  }
}

// ---------------- final: inline ref-stats reduce + edge + local avg ----------
__global__ void __launch_bounds__(256)
k_final(const float* __restrict__ epre, const float* __restrict__ logits,
        const float* __restrict__ partDW, const float* __restrict__ rg_g,
        const float* __restrict__ rg_b, const float* __restrict__ pw_w,
        const float* __restrict__ pw_b, const float* __restrict__ alpha,
        float* __restrict__ outp){
  __shared__ float sst[16];
  __shared__ float part[4];
  __shared__ float edge_s[2];
  reduce_part(partDW, 128, sst);
  int tid = threadIdx.x;
  int pixl = tid >> 7, c = tid & 127;
  int pix = blockIdx.x*2 + pixl;
  int b = pix >> 12, p = pix & 4095, yy = p >> 6, xx = p & 63;
  int g = c >> 5;
  float m = sst[b*8 + g*2]   * (1.f/NG);
  float v = sst[b*8 + g*2+1] * (1.f/NG) - m*m;
  float e = epre[(size_t)pix*128+c];
  float en = siluf((e-m)*rsqrtf(v+1e-5f)*rg_g[c] + rg_b[c]);
  float pv = en * pw_w[c];
  pv += __shfl_xor(pv,1);  pv += __shfl_xor(pv,2);  pv += __shfl_xor(pv,4);
  pv += __shfl_xor(pv,8);  pv += __shfl_xor(pv,16); pv += __shfl_xor(pv,32);
  if ((tid & 63) == 0) part[tid>>6] = pv;
  __syncthreads();
  if (tid < 2) edge_s[tid] = sigm(part[tid*2] + part[tid*2+1] + pw_b[0]);
  __syncthreads();
  if (c < 10){
    float ed = edge_s[pixl];
    int o = c;
    float lg = logits[(size_t)pix*16 + o];
    float loc = 0.f;
    for (int dy = -1; dy <= 1; dy++){
      int ny = yy+dy; if (ny < 0 || ny > 63) continue;
      for (int dx = -1; dx <= 1; dx++){
        int nx = xx+dx; if (nx < 0 || nx > 63) continue;
        loc += logits[(size_t)((b<<12)|(ny<<6)|nx)*16 + o];
      }
    }
    loc *= (1.f/9.f);
    outp[(size_t)((b*10+o)<<12) + p] = lg + alpha[0]*(1.f-ed)*(loc - lg);
  }
}

extern "C" void kernel_launch(void* const* d_in, const int* in_sizes, int n_in,
                              void* d_out, int out_size, void* d_ws, size_t ws_size,
                              hipStream_t stream){
  const float* x          = (const float*)d_in[0];
  const float* pe_w       = (const float*)d_in[1];
  const float* pe_b       = (const float*)d_in[2];
  const float* pe_gn_g    = (const float*)d_in[3];
  const float* pe_gn_b    = (const float*)d_in[4];
  const float* spa_in_w   = (const float*)d_in[5];
  const float* spa_conv_w = (const float*)d_in[6];
  const float* spa_conv_b = (const float*)d_in[7];
  const float* spa_xproj_w= (const float*)d_in[8];
  const float* spa_dt_w   = (const float*)d_in[9];
  const float* spa_dt_b   = (const float*)d_in[10];
  const float* spa_Alog   = (const float*)d_in[11];
  const float* spa_D      = (const float*)d_in[12];
  const float* spa_out_w  = (const float*)d_in[13];
  const float* spa_gn_g   = (const float*)d_in[14];
  const float* spa_gn_b   = (const float*)d_in[15];
  const float* spe_in_w   = (const float*)d_in[16];
  const float* spe_conv_w = (const float*)d_in[17];
  const float* spe_conv_b = (const float*)d_in[18];
  const float* spe_xproj_w= (const float*)d_in[19];
  const float* spe_dt_w   = (const float*)d_in[20];
  const float* spe_dt_b   = (const float*)d_in[21];
  const float* spe_Alog   = (const float*)d_in[22];
  const float* spe_D      = (const float*)d_in[23];
  const float* spe_out_w  = (const float*)d_in[24];
  const float* spe_gn_g   = (const float*)d_in[25];
  const float* spe_gn_b   = (const float*)d_in[26];
  const float* fuse_w     = (const float*)d_in[27];
  const float* cls_w      = (const float*)d_in[28];
  const float* cls_b      = (const float*)d_in[29];
  const float* ref_dw_w   = (const float*)d_in[30];
  const float* ref_gn_g   = (const float*)d_in[31];
  const float* ref_gn_b   = (const float*)d_in[32];
  const float* ref_pw_w   = (const float*)d_in[33];
  const float* ref_pw_b   = (const float*)d_in[34];
  const float* alpha      = (const float*)d_in[35];
  float* ws  = (float*)d_ws;
  float* out = (float*)d_out;

  float* Pb    = ws + WS_POFF;   // hs aliases Pb (scan2 in-place)
  float* Qb    = ws + WS_QOFF;   // Q dead after scan2 (proj2/logits written later)
  float* HSb   = Pb;
  float* dely  = ws + WS_Y;      // delta; scan3 writes y over it
  float* partPE  = ws + WS_Y;          // consumed by k_xz before k_projc overwrites
  float* partSPA = ws + WS_POFF;       // hs dead after scan3
  float* partSPE = ws + WS_POFF + 16384;
  float* partDW  = ws + WS_POFF + 65536;
  float* proj  = ws + WS_PROJ;
  float* xc2   = ws + WS_XC;           // xc dead after scan3
  float* zsil2 = ws + WS_XZD;          // xzd dead after projc
  float* proj2 = ws + WS_QOFF;         // Q dead after scan2
  float* epre  = ws + WS_Y;            // y dead after outproj

  k_pe<<<dim3(2,256),256,0,stream>>>(x, pe_w, pe_b, ws+WS_H1PRE, partPE);
  k_xz<<<dim3(8,128),256,0,stream>>>(ws+WS_H1PRE, spa_in_w, partPE,
      pe_gn_g, pe_gn_b, ws+WS_H1, ws+WS_XZD, ws+WS_ZSIL);
  k_projc<<<512,256,0,stream>>>(ws+WS_XZD, spa_conv_w, spa_conv_b, spa_xproj_w,
      spa_dt_w, spa_dt_b, spa_Alog, ws+WS_XC, proj, dely, Pb, Qb);
  k_scan2<<<512,256,0,stream>>>(Pb, Qb, HSb);
  k_scan3<<<2048,256,0,stream>>>(dely, proj, ws+WS_XC, ws+WS_ZSIL,
      spa_Alog, spa_D, HSb, dely);
  k_outproj<<<dim3(2,256),256,0,stream>>>(dely, spa_out_w, ws+WS_H1PRE, partSPA);
  k_spe_ab<<<512,256,0,stream>>>(ws+WS_H1, spe_in_w, spe_conv_w, spe_conv_b,
      spe_xproj_w, xc2, zsil2, proj2);
  k_spe_cd<<<512,256,0,stream>>>(xc2, zsil2, proj2, spe_dt_w, spe_dt_b,
      spe_Alog, spe_D, spe_out_w, ws+WS_Y2, partSPE);
  k_fusedw<<<256,256,0,stream>>>(ws+WS_H1, ws+WS_H1PRE, ws+WS_Y2,
      partSPA, partSPE, spa_gn_g, spa_gn_b, spe_gn_g, spe_gn_b,
      fuse_w, cls_w, cls_b, ref_dw_w, ws+WS_LOG, epre, partDW);
  k_final<<<4096,256,0,stream>>>(epre, ws+WS_LOG, partDW,
      ref_gn_g, ref_gn_b, ref_pw_w, ref_pw_b, alpha, out);
  (void)in_sizes; (void)n_in; (void)out_size; (void)ws_size;
}

// Round 14
// 379.043 us; speedup vs baseline: 1.0363x; 1.0363x over previous
//
#include <hip/hip_runtime.h>
#include <math.h>

#define DEV __device__ __forceinline__

DEV float sigm(float x){ return 1.f/(1.f+__expf(-x)); }
DEV float siluf(float x){ return x * sigm(x); }
DEV float softplusf(float x){ return x > 20.f ? x : log1pf(__expf(x)); }

static constexpr float NG = 131072.0f;   // group-norm element count per (b,g)
static constexpr float LOG2E = 1.4426950408889634f;

// ---- workspace layout (offsets in floats) ----
static constexpr size_t WS_H1    = 0;          // B*HW*128
static constexpr size_t WS_H1PRE = 1048576;    // h1pre; later yproj
static constexpr size_t WS_XC    = 2097152;    // spa xc; later spe xc2
static constexpr size_t WS_ZSIL  = 4194304;    // spa zsil
static constexpr size_t WS_XZD   = 6291456;    // dense xzd [8192][256] (2M); later spe zsil2
static constexpr size_t WS_QOFF  = 8388608;    // scan Q (2M); later proj2/logits (after scan2)
static constexpr size_t WS_LOG   = 8650752;    // logits (k_fusedw; Q/proj2 dead by then)
static constexpr size_t WS_Y     = 10485760;   // partPE; delta (aliases y); y; later epre
static constexpr size_t WS_POFF  = 12582912;   // scan P / hs (2M); after scan3: partials
static constexpr size_t WS_Y2    = 14155776;   // B*HW*128 (spe_cd; hs dead)
static constexpr size_t WS_PROJ  = 15204352;   // proj[8192][40]

// ---- in-kernel partial reduce: part[b*rowsPerB+row][8] -> dst16[16] ----
DEV void reduce_part(const float* __restrict__ part, int rowsPerB, float* dst16){
  int tid = threadIdx.x;
  int p = tid >> 4, sl = tid & 15;      // p = b*8 + j
  int b = p >> 3, j = p & 7;
  float s = 0.f;
  for (int row = sl; row < rowsPerB; row += 16)
    s += part[((size_t)b*rowsPerB + row)*8 + j];
  s += __shfl_xor(s,1); s += __shfl_xor(s,2);
  s += __shfl_xor(s,4); s += __shfl_xor(s,8);
  if (sl == 0) dst16[p] = s;
  __syncthreads();
}

// ---------------- pe 1x1 conv (tiled GEMM 32x64) + GN partials ---------------
__global__ void __launch_bounds__(256)
k_pe(const float* __restrict__ x, const float* __restrict__ pe_w,
     const float* __restrict__ pe_b, float* __restrict__ h1pre,
     float* __restrict__ part){
  __shared__ float As[16][36];
  __shared__ float Bs[16][64];
  __shared__ float red1[2][4], red2[2][4];
  int tid = threadIdx.x;
  int nx = blockIdx.x, my = blockIdx.y;
  int m0 = my*32, n0 = nx*64;
  int b = m0 >> 12, pl0 = m0 & 4095;
  int tx = tid & 15, ty = tid >> 4;
  float acc[2][4];
  #pragma unroll
  for (int i = 0; i < 2; i++)
    #pragma unroll
    for (int j = 0; j < 4; j++) acc[i][j] = 0.f;
  for (int k0 = 0; k0 < 128; k0 += 16){
    if (tid < 128){
      int k = tid >> 3, mm = (tid & 7)*4;
      float4 a = *(const float4*)(x + ((size_t)b*128 + k0+k)*4096 + pl0 + mm);
      *(float4*)&As[k][mm] = a;
    }
    {
      int n = tid >> 2, kq = (tid & 3)*4;
      float4 a = *(const float4*)(pe_w + (size_t)(n0+n)*128 + k0 + kq);
      Bs[kq+0][n] = a.x; Bs[kq+1][n] = a.y; Bs[kq+2][n] = a.z; Bs[kq+3][n] = a.w;
    }
    __syncthreads();
    #pragma unroll
    for (int k = 0; k < 16; k++){
      float2 av = *(const float2*)&As[k][ty*2];
      float4 bv = *(const float4*)&Bs[k][tx*4];
      acc[0][0] += av.x*bv.x; acc[0][1] += av.x*bv.y; acc[0][2] += av.x*bv.z; acc[0][3] += av.x*bv.w;
      acc[1][0] += av.y*bv.x; acc[1][1] += av.y*bv.y; acc[1][2] += av.y*bv.z; acc[1][3] += av.y*bv.w;
    }
    __syncthreads();
  }
  float4 bias = *(const float4*)(pe_b + n0 + tx*4);
  float s1 = 0.f, s2 = 0.f;
  #pragma unroll
  for (int i = 0; i < 2; i++){
    float4 st;
    st.x = acc[i][0]+bias.x; st.y = acc[i][1]+bias.y;
    st.z = acc[i][2]+bias.z; st.w = acc[i][3]+bias.w;
    s1 += st.x+st.y+st.z+st.w;
    s2 += st.x*st.x + st.y*st.y + st.z*st.z + st.w*st.w;
    *(float4*)(h1pre + (size_t)(m0 + ty*2 + i)*128 + n0 + tx*4) = st;
  }
  s1 += __shfl_xor(s1,1);  s2 += __shfl_xor(s2,1);
  s1 += __shfl_xor(s1,2);  s2 += __shfl_xor(s2,2);
  s1 += __shfl_xor(s1,4);  s2 += __shfl_xor(s2,4);
  s1 += __shfl_xor(s1,16); s2 += __shfl_xor(s2,16);
  s1 += __shfl_xor(s1,32); s2 += __shfl_xor(s2,32);
  int lane = tid & 63, w = tid >> 6;
  if ((lane & 55) == 0){
    int gl = (lane >> 3) & 1;
    red1[gl][w] = s1; red2[gl][w] = s2;
  }
  __syncthreads();
  if (tid < 8){
    int gg = tid >> 1, which = tid & 1;
    int gl = gg - nx*2;
    float v = 0.f;
    if (gl == 0 || gl == 1){
      v = which ? (red2[gl][0]+red2[gl][1]+red2[gl][2]+red2[gl][3])
                : (red1[gl][0]+red1[gl][1]+red1[gl][2]+red1[gl][3]);
    }
    int pblk = b*256 + (my & 127)*2 + nx;
    part[(size_t)pblk*8 + tid] = v;
  }
}

// ---------------- spa in-proj GEMM 64x64, inline pe-stats + GN+silu ----------
// grid dim3(8,128). Dense xzd output.
__global__ void __launch_bounds__(256)
k_xz(const float* __restrict__ h1pre, const float* __restrict__ in_w,
     const float* __restrict__ partPE, const float* __restrict__ gng,
     const float* __restrict__ gnb, float* __restrict__ h1,
     float* __restrict__ xzd, float* __restrict__ zsil){
  __shared__ float As[16][68];
  __shared__ float Bs[16][64];
  __shared__ float sst[16];
  reduce_part(partPE, 256, sst);
  int tid = threadIdx.x;
  int m0 = blockIdx.y*64, n0 = blockIdx.x*64;
  int tx = tid & 15, ty = tid >> 4;
  float acc[4][4];
  #pragma unroll
  for (int i = 0; i < 4; i++)
    #pragma unroll
    for (int j = 0; j < 4; j++) acc[i][j] = 0.f;
  for (int k0 = 0; k0 < 128; k0 += 16){
    {
      int m = tid >> 2, kk = (tid & 3)*4;
      int pixm = m0 + m, c0 = k0 + kk;
      int bb = pixm >> 12, g = c0 >> 5;
      float4 a = *(const float4*)(h1pre + (size_t)pixm*128 + c0);
      float mu = sst[bb*8 + g*2] * (1.f/NG);
      float var = sst[bb*8 + g*2 + 1] * (1.f/NG) - mu*mu;
      float rs = rsqrtf(var + 1e-5f);
      float4 gg = *(const float4*)(gng + c0);
      float4 gb = *(const float4*)(gnb + c0);
      float4 v;
      v.x = siluf((a.x-mu)*rs*gg.x + gb.x);
      v.y = siluf((a.y-mu)*rs*gg.y + gb.y);
      v.z = siluf((a.z-mu)*rs*gg.z + gb.z);
      v.w = siluf((a.w-mu)*rs*gg.w + gb.w);
      As[kk+0][m] = v.x; As[kk+1][m] = v.y; As[kk+2][m] = v.z; As[kk+3][m] = v.w;
      if (blockIdx.x == 0) *(float4*)(h1 + (size_t)pixm*128 + c0) = v;
    }
    {
      int n = tid >> 2, kq = (tid & 3)*4;
      float4 a = *(const float4*)(in_w + (size_t)(n0+n)*128 + k0 + kq);
      Bs[kq+0][n] = a.x; Bs[kq+1][n] = a.y; Bs[kq+2][n] = a.z; Bs[kq+3][n] = a.w;
    }
    __syncthreads();
    #pragma unroll
    for (int k = 0; k < 16; k++){
      float4 av = *(const float4*)&As[k][ty*4];
      float4 bv = *(const float4*)&Bs[k][tx*4];
      acc[0][0] += av.x*bv.x; acc[0][1] += av.x*bv.y; acc[0][2] += av.x*bv.z; acc[0][3] += av.x*bv.w;
      acc[1][0] += av.y*bv.x; acc[1][1] += av.y*bv.y; acc[1][2] += av.y*bv.z; acc[1][3] += av.y*bv.w;
      acc[2][0] += av.z*bv.x; acc[2][1] += av.z*bv.y; acc[2][2] += av.z*bv.z; acc[2][3] += av.z*bv.w;
      acc[3][0] += av.w*bv.x; acc[3][1] += av.w*bv.y; acc[3][2] += av.w*bv.z; acc[3][3] += av.w*bv.w;
    }
    __syncthreads();
  }
  if (n0 < 256){
    #pragma unroll
    for (int i = 0; i < 4; i++){
      float4 st; st.x = acc[i][0]; st.y = acc[i][1]; st.z = acc[i][2]; st.w = acc[i][3];
      *(float4*)(xzd + (size_t)(m0 + ty*4 + i)*256 + n0 + tx*4) = st;
    }
  } else {
    #pragma unroll
    for (int i = 0; i < 4; i++){
      float4 st;
      st.x = siluf(acc[i][0]); st.y = siluf(acc[i][1]);
      st.z = siluf(acc[i][2]); st.w = siluf(acc[i][3]);
      *(float4*)(zsil + (size_t)(m0 + ty*4 + i)*256 + (n0-256) + tx*4) = st;
    }
  }
}

// ---------------- fused conv + x-proj + delta (NO scan) ----------------
// grid 512; block = 16 tokens.
__global__ void __launch_bounds__(256)
k_projc(const float* __restrict__ xzd, const float* __restrict__ cw,
        const float* __restrict__ cb, const float* __restrict__ xpw,
        const float* __restrict__ dtw, const float* __restrict__ dtb,
        float* __restrict__ xc, float* __restrict__ proj,
        float* __restrict__ delta){
  __shared__ float xct[16*260];
  __shared__ float s_dt[16][9];
  int tid = threadIdx.x;
  int m0 = blockIdx.x * 16;
  // phase A: depthwise conv K=4 + silu
  {
    int slot = tid >> 6, lane = tid & 63;
    int d4 = lane*4;
    float4 cbv = *(const float4*)(cb + d4);
    float4 cw0 = *(const float4*)(cw + (size_t)(d4+0)*4);
    float4 cw1 = *(const float4*)(cw + (size_t)(d4+1)*4);
    float4 cw2 = *(const float4*)(cw + (size_t)(d4+2)*4);
    float4 cw3 = *(const float4*)(cw + (size_t)(d4+3)*4);
    const float* c0p = (const float*)&cw0;
    const float* c1p = (const float*)&cw1;
    const float* c2p = (const float*)&cw2;
    const float* c3p = (const float*)&cw3;
    for (int i = 0; i < 4; i++){
      int t = slot*4 + i;
      int tok = m0 + t;
      int l = tok & 4095;
      float4 acc = cbv;
      #pragma unroll
      for (int k = 0; k < 4; k++){
        int ls = l - 3 + k;
        if (ls >= 0){
          float4 xv = *(const float4*)(xzd + (size_t)(tok-3+k)*256 + d4);
          acc.x += xv.x * c0p[k];
          acc.y += xv.y * c1p[k];
          acc.z += xv.z * c2p[k];
          acc.w += xv.w * c3p[k];
        }
      }
      float4 s;
      s.x = siluf(acc.x); s.y = siluf(acc.y); s.z = siluf(acc.z); s.w = siluf(acc.w);
      *(float4*)&xct[t*260 + d4] = s;
      *(float4*)(xc + (size_t)tok*256 + d4) = s;
    }
  }
  __syncthreads();
  // phase B: x-proj -> proj global + dt inputs to LDS
  {
    int t = tid & 15, jq = tid >> 4;
    int tok = m0 + t;
    float a0 = 0.f, a1 = 0.f, a2 = 0.f;
    for (int k0 = 0; k0 < 256; k0 += 4){
      float4 av = *(const float4*)&xct[t*260 + k0];
      float4 w0 = *(const float4*)(xpw + (size_t)jq*256 + k0);
      float4 w1 = *(const float4*)(xpw + (size_t)(jq+16)*256 + k0);
      a0 += av.x*w0.x + av.y*w0.y + av.z*w0.z + av.w*w0.w;
      a1 += av.x*w1.x + av.y*w1.y + av.z*w1.z + av.w*w1.w;
      if (jq < 8){
        float4 w2 = *(const float4*)(xpw + (size_t)(jq+32)*256 + k0);
        a2 += av.x*w2.x + av.y*w2.y + av.z*w2.z + av.w*w2.w;
      }
    }
    float* pr = proj + (size_t)tok*40;
    pr[jq] = a0;
    pr[jq+16] = a1;
    if (jq < 8){ pr[jq+32] = a2; s_dt[t][jq] = a0; }
  }
  __syncthreads();
  // phase C: delta only (thread = d)
  {
    int d = tid;
    const float4* wr = (const float4*)(dtw + (size_t)d*8);
    float4 w0 = wr[0], w1 = wr[1];
    float bd = dtb[d];
    for (int t = 0; t < 16; t++){
      float v = bd + s_dt[t][0]*w0.x + s_dt[t][1]*w0.y + s_dt[t][2]*w0.z + s_dt[t][3]*w0.w
                   + s_dt[t][4]*w1.x + s_dt[t][5]*w1.y + s_dt[t][6]*w1.z + s_dt[t][7]*w1.w;
      delta[(size_t)(m0+t)*256 + d] = softplusf(v);
    }
  }
}

// ---------------- scan phase 1: thread=(d, n-quartet), 16-step chunks --------
// grid 2048 = 2b x 256chunk x 4dblk (r11-proven).
__global__ void __launch_bounds__(256)
k_scan1(const float* __restrict__ delta, const float* __restrict__ proj,
        const float* __restrict__ xc, const float* __restrict__ Alog,
        float* __restrict__ P, float* __restrict__ Q){
  int blk = blockIdx.x;
  int dblk = blk & 3;
  int bc = blk >> 2;
  int b = bc >> 8, chunk = bc & 255;
  int tid = threadIdx.x;
  int dl = tid >> 2, ng = tid & 3;
  int d = dblk*64 + dl;
  float4 a4 = *(const float4*)(Alog + (size_t)d*16 + ng*4);
  float An[4] = {-__expf(a4.x)*LOG2E, -__expf(a4.y)*LOG2E,
                 -__expf(a4.z)*LOG2E, -__expf(a4.w)*LOG2E};
  float Pv[4] = {1.f,1.f,1.f,1.f}, Qv[4] = {0.f,0.f,0.f,0.f};
  size_t row0 = (size_t)(b*4096 + chunk*16);
  for (int l = 0; l < 16; l++){
    size_t r = row0 + l;
    float dv = delta[r*256 + d];
    float xv = xc[r*256 + d];
    float4 bm = *(const float4*)(proj + r*40 + 8 + ng*4);
    float dBx = dv*xv;
    float bmv[4] = {bm.x, bm.y, bm.z, bm.w};
    #pragma unroll
    for (int k = 0; k < 4; k++){
      float a = exp2f(dv*An[k]);
      Qv[k] = a*Qv[k] + bmv[k]*dBx;
      Pv[k] *= a;
    }
  }
  size_t o = (size_t)bc*4096 + dblk*1024 + tid*4;
  float4 pv; pv.x=Pv[0]; pv.y=Pv[1]; pv.z=Pv[2]; pv.w=Pv[3];
  float4 qv; qv.x=Qv[0]; qv.y=Qv[1]; qv.z=Qv[2]; qv.w=Qv[3];
  *(float4*)(P + o) = pv;
  *(float4*)(Q + o) = qv;
}

// ---------------- scan phase 2: 256-chunk scan; lane owns 4 chunks -----------
__global__ void __launch_bounds__(256)
k_scan2(const float* __restrict__ P, const float* __restrict__ Q,
        float* __restrict__ hs){
  __shared__ float Ps[256][17], Qs[256][17];
  int tid = threadIdx.x;
  int b = blockIdx.x >> 8;
  int dn0 = (blockIdx.x & 255) * 16;
  for (int i = tid; i < 1024; i += 256){
    int ch = i >> 2, g = (i & 3)*4;
    size_t gaddr = (size_t)(b*256+ch)*4096 + dn0 + g;
    float4 p = *(const float4*)(P + gaddr);
    float4 q = *(const float4*)(Q + gaddr);
    Ps[ch][g]=p.x; Ps[ch][g+1]=p.y; Ps[ch][g+2]=p.z; Ps[ch][g+3]=p.w;
    Qs[ch][g]=q.x; Qs[ch][g+1]=q.y; Qs[ch][g+2]=q.z; Qs[ch][g+3]=q.w;
  }
  __syncthreads();
  int lane = tid & 63, wv = tid >> 6;
  for (int rep = 0; rep < 4; rep++){
    int c = wv*4 + rep;
    float p0 = Ps[4*lane+0][c], q0 = Qs[4*lane+0][c];
    float p1 = Ps[4*lane+1][c], q1 = Qs[4*lane+1][c];
    float p2 = Ps[4*lane+2][c], q2 = Qs[4*lane+2][c];
    float p3 = Ps[4*lane+3][c], q3 = Qs[4*lane+3][c];
    float p = p0, q = q0;
    q = p1*q + q1; p *= p1;
    q = p2*q + q2; p *= p2;
    q = p3*q + q3; p *= p3;
    #pragma unroll
    for (int off = 1; off < 64; off <<= 1){
      float pp = __shfl_up(p, off);
      float qp = __shfl_up(q, off);
      if (lane >= off){ q = p*qp + q; p = p*pp; }
    }
    float h0 = __shfl_up(q, 1);
    if (lane == 0) h0 = 0.f;
    float h1 = p0*h0 + q0;
    float h2 = p1*h1 + q1;
    float h3 = p2*h2 + q2;
    Ps[4*lane+0][c] = h0;
    Ps[4*lane+1][c] = h1;
    Ps[4*lane+2][c] = h2;
    Ps[4*lane+3][c] = h3;
  }
  __syncthreads();
  for (int i = tid; i < 1024; i += 256){
    int ch = i >> 2, g = (i & 3)*4;
    size_t gaddr = (size_t)(b*256+ch)*4096 + dn0 + g;
    float4 h;
    h.x = Ps[ch][g]; h.y = Ps[ch][g+1]; h.z = Ps[ch][g+2]; h.w = Ps[ch][g+3];
    *(float4*)(hs + gaddr) = h;
  }
}

// ---------------- scan phase 3: replay + y; thread=(d, n-quartet) ------------
__global__ void __launch_bounds__(256)
k_scan3(const float* __restrict__ delta, const float* __restrict__ proj,
        const float* __restrict__ xc, const float* __restrict__ zsil,
        const float* __restrict__ Alog, const float* __restrict__ Dv,
        const float* __restrict__ hs, float* __restrict__ y){
  int blk = blockIdx.x;
  int dblk = blk & 3;
  int bc = blk >> 2;
  int b = bc >> 8, chunk = bc & 255;
  int tid = threadIdx.x;
  int dl = tid >> 2, ng = tid & 3;
  int d = dblk*64 + dl;
  float4 a4 = *(const float4*)(Alog + (size_t)d*16 + ng*4);
  float An[4] = {-__expf(a4.x)*LOG2E, -__expf(a4.y)*LOG2E,
                 -__expf(a4.z)*LOG2E, -__expf(a4.w)*LOG2E};
  float Dd = Dv[d];
  float h[4];
  {
    size_t o = (size_t)bc*4096 + dblk*1024 + tid*4;
    float4 hv = *(const float4*)(hs + o);
    h[0]=hv.x; h[1]=hv.y; h[2]=hv.z; h[3]=hv.w;
  }
  size_t row0 = (size_t)(b*4096 + chunk*16);
  for (int l = 0; l < 16; l++){
    size_t r = row0 + l;
    float dv = delta[r*256 + d];
    float xv = xc[r*256 + d];
    float4 bm = *(const float4*)(proj + r*40 + 8 + ng*4);
    float4 cm = *(const float4*)(proj + r*40 + 24 + ng*4);
    float dBx = dv*xv;
    float bmv[4] = {bm.x, bm.y, bm.z, bm.w};
    float cmv[4] = {cm.x, cm.y, cm.z, cm.w};
    float ys = 0.f;
    #pragma unroll
    for (int k = 0; k < 4; k++){
      float a = exp2f(dv*An[k]);
      h[k] = a*h[k] + bmv[k]*dBx;
      ys += h[k]*cmv[k];
    }
    ys += __shfl_xor(ys, 1);
    ys += __shfl_xor(ys, 2);
    if (ng == 0){
      float zv = zsil[r*256 + d];
      y[r*256 + d] = (ys + Dd*xv) * zv;
    }
  }
}

// ---------------- spa out-proj: tiled GEMM 32x64 + GN partials ---------------
__global__ void __launch_bounds__(256)
k_outproj(const float* __restrict__ y, const float* __restrict__ out_w,
          float* __restrict__ yproj, float* __restrict__ part){
  __shared__ float As[16][36];
  __shared__ float Bs[16][64];
  __shared__ float red1[2][4], red2[2][4];
  int tid = threadIdx.x;
  int nx = blockIdx.x, my = blockIdx.y;
  int m0 = my*32, n0 = nx*64;
  int b = m0 >> 12;
  int tx = tid & 15, ty = tid >> 4;
  float acc[2][4];
  #pragma unroll
  for (int i = 0; i < 2; i++)
    #pragma unroll
    for (int j = 0; j < 4; j++) acc[i][j] = 0.f;
  for (int k0 = 0; k0 < 256; k0 += 16){
    if (tid < 128){
      int m = tid >> 2, kk = (tid & 3)*4;
      float4 a = *(const float4*)(y + (size_t)(m0+m)*256 + k0+kk);
      As[kk+0][m] = a.x; As[kk+1][m] = a.y; As[kk+2][m] = a.z; As[kk+3][m] = a.w;
    }
    {
      int n = tid >> 2, kq = (tid & 3)*4;
      float4 a = *(const float4*)(out_w + (size_t)(n0+n)*256 + k0 + kq);
      Bs[kq+0][n] = a.x; Bs[kq+1][n] = a.y; Bs[kq+2][n] = a.z; Bs[kq+3][n] = a.w;
    }
    __syncthreads();
    #pragma unroll
    for (int k = 0; k < 16; k++){
      float2 av = *(const float2*)&As[k][ty*2];
      float4 bv = *(const float4*)&Bs[k][tx*4];
      acc[0][0] += av.x*bv.x; acc[0][1] += av.x*bv.y; acc[0][2] += av.x*bv.z; acc[0][3] += av.x*bv.w;
      acc[1][0] += av.y*bv.x; acc[1][1] += av.y*bv.y; acc[1][2] += av.y*bv.z; acc[1][3] += av.y*bv.w;
    }
    __syncthreads();
  }
  float s1 = 0.f, s2 = 0.f;
  #pragma unroll
  for (int i = 0; i < 2; i++){
    float4 st; st.x = acc[i][0]; st.y = acc[i][1]; st.z = acc[i][2]; st.w = acc[i][3];
    s1 += st.x+st.y+st.z+st.w;
    s2 += st.x*st.x + st.y*st.y + st.z*st.z + st.w*st.w;
    *(float4*)(yproj + (size_t)(m0 + ty*2 + i)*128 + n0 + tx*4) = st;
  }
  s1 += __shfl_xor(s1,1);  s2 += __shfl_xor(s2,1);
  s1 += __shfl_xor(s1,2);  s2 += __shfl_xor(s2,2);
  s1 += __shfl_xor(s1,4);  s2 += __shfl_xor(s2,4);
  s1 += __shfl_xor(s1,16); s2 += __shfl_xor(s2,16);
  s1 += __shfl_xor(s1,32); s2 += __shfl_xor(s2,32);
  int lane = tid & 63, w = tid >> 6;
  if ((lane & 55) == 0){
    int gl = (lane >> 3) & 1;
    red1[gl][w] = s1; red2[gl][w] = s2;
  }
  __syncthreads();
  if (tid < 8){
    int gg = tid >> 1, which = tid & 1;
    int gl = gg - nx*2;
    float v = 0.f;
    if (gl == 0 || gl == 1){
      v = which ? (red2[gl][0]+red2[gl][1]+red2[gl][2]+red2[gl][3])
                : (red1[gl][0]+red1[gl][1]+red1[gl][2]+red1[gl][3]);
    }
    int pblk = b*256 + (my & 127)*2 + nx;
    part[(size_t)pblk*8 + tid] = v;
  }
}

// ---------------- spe A+B: in-proj + conv + silu + x-proj --------------------
__global__ void __launch_bounds__(256)
k_spe_ab(const float* __restrict__ h1, const float* __restrict__ in_w,
         const float* __restrict__ conv_w, const float* __restrict__ conv_b,
         const float* __restrict__ xpw, float* __restrict__ xc2,
         float* __restrict__ zsil2, float* __restrict__ proj2){
  __shared__ float s_in[4][128];
  __shared__ float s_xc[64][66];
  int tid = threadIdx.x;
  int w = tid >> 6, lane = tid & 63;
  {
    float wx[32], wz[32];
    const float4* rx = (const float4*)(in_w + (size_t)lane*32);
    const float4* rz = (const float4*)(in_w + (size_t)(64+lane)*32);
    #pragma unroll
    for (int k = 0; k < 8; k++){
      float4 a = rx[k]; wx[k*4]=a.x; wx[k*4+1]=a.y; wx[k*4+2]=a.z; wx[k*4+3]=a.w;
      float4 b = rz[k]; wz[k*4]=b.x; wz[k*4+1]=b.y; wz[k*4+2]=b.z; wz[k*4+3]=b.w;
    }
    float4 cwv = ((const float4*)conv_w)[lane];
    float cbv = conv_b[lane];
    for (int i = 0; i < 4; i++){
      int pix = blockIdx.x*16 + w*4 + i;
      float2 hv = ((const float2*)(h1 + (size_t)pix*128))[lane];
      s_in[w][2*lane] = hv.x; s_in[w][2*lane+1] = hv.y;
      float xpr[4], zs[4];
      #pragma unroll
      for (int l = 0; l < 4; l++){
        const float4* sv = (const float4*)&s_in[w][l*32];
        float ax = 0.f, az = 0.f;
        #pragma unroll
        for (int c4 = 0; c4 < 8; c4++){
          float4 v = sv[c4];
          ax += v.x*wx[c4*4] + v.y*wx[c4*4+1] + v.z*wx[c4*4+2] + v.w*wx[c4*4+3];
          az += v.x*wz[c4*4] + v.y*wz[c4*4+1] + v.z*wz[c4*4+2] + v.w*wz[c4*4+3];
        }
        xpr[l] = ax; zs[l] = siluf(az);
      }
      #pragma unroll
      for (int l = 0; l < 4; l++){
        float v = cbv;
        if (l >= 3) v += xpr[l-3]*cwv.x;
        if (l >= 2) v += xpr[l-2]*cwv.y;
        if (l >= 1) v += xpr[l-1]*cwv.z;
        v += xpr[l]*cwv.w;
        float sx = siluf(v);
        int t = (w*4+i)*4 + l;
        int tok = blockIdx.x*64 + t;
        s_xc[t][lane] = sx;
        xc2 [(size_t)tok*64 + lane] = sx;
        zsil2[(size_t)tok*64 + lane] = zs[l];
      }
    }
  }
  __syncthreads();
  {
    int t = lane;
    float a[9];
    #pragma unroll
    for (int j = 0; j < 9; j++) a[j] = 0.f;
    for (int k = 0; k < 64; k++){
      float xk = s_xc[t][k];
      #pragma unroll
      for (int j = 0; j < 9; j++){
        int ja = w*9 + j; if (ja > 33) ja = 33;
        a[j] += xk * xpw[(size_t)ja*64 + k];
      }
    }
    float* pr = proj2 + (size_t)(blockIdx.x*64 + t)*36;
    #pragma unroll
    for (int j = 0; j < 9; j++){
      int ja = w*9 + j;
      if (ja < 34) pr[ja] = a[j];
    }
  }
}

// ---------------- spe C+D: scan + gate -> LDS -> out-proj + GN partials ------
__global__ void __launch_bounds__(256)
k_spe_cd(const float* __restrict__ xc2, const float* __restrict__ zsil2,
         const float* __restrict__ proj, const float* __restrict__ dt_w,
         const float* __restrict__ dt_b, const float* __restrict__ Alog,
         const float* __restrict__ Dvec, const float* __restrict__ out_w,
         float* __restrict__ y2, float* __restrict__ part){
  __shared__ float s_y[64][68];
  __shared__ float ldsWT[64*32];
  __shared__ float bst[8];
  int tid = threadIdx.x;
  int w = tid >> 6, lane = tid & 63;
  for (int i = tid; i < 2048; i += 256){
    int c2 = i >> 6, dd = i & 63;
    ldsWT[dd*32 + c2] = out_w[i];
  }
  if (tid < 8) bst[tid] = 0.f;
  // phase C
  {
    float2 dtwv = ((const float2*)dt_w)[lane];
    float dbv = dt_b[lane], Dd = Dvec[lane];
    float An[16];
    const float4* ar = (const float4*)(Alog + (size_t)lane*16);
    #pragma unroll
    for (int k = 0; k < 4; k++){
      float4 a = ar[k];
      An[k*4]   = -__expf(a.x)*LOG2E; An[k*4+1] = -__expf(a.y)*LOG2E;
      An[k*4+2] = -__expf(a.z)*LOG2E; An[k*4+3] = -__expf(a.w)*LOG2E;
    }
    for (int i = 0; i < 4; i++){
      int pix = blockIdx.x*16 + w*4 + i;
      float h[16];
      #pragma unroll
      for (int n = 0; n < 16; n++) h[n] = 0.f;
      #pragma unroll
      for (int l = 0; l < 4; l++){
        int tok = pix*4 + l;
        float pj[36];
        {
          const float4* pr = (const float4*)(proj + (size_t)tok*36);
          #pragma unroll
          for (int k = 0; k < 9; k++){
            float4 v = pr[k];
            pj[k*4]=v.x; pj[k*4+1]=v.y; pj[k*4+2]=v.z; pj[k*4+3]=v.w;
          }
        }
        float xv = xc2[(size_t)tok*64 + lane];
        float zv = zsil2[(size_t)tok*64 + lane];
        float dt = softplusf(dbv + pj[0]*dtwv.x + pj[1]*dtwv.y);
        float ys = 0.f;
        #pragma unroll
        for (int n = 0; n < 16; n++){
          float a = exp2f(dt * An[n]);
          h[n] = a*h[n] + dt * pj[2+n] * xv;
          ys += h[n] * pj[18+n];
        }
        s_y[(w*4+i)*4 + l][lane] = (ys + Dd*xv) * zv;
      }
    }
  }
  __syncthreads();
  // phase D
  {
    int c2 = lane & 31, slot = lane >> 5;
    int tl0 = w*16 + slot;
    float acc[8];
    #pragma unroll
    for (int i = 0; i < 8; i++) acc[i] = 0.f;
    for (int dd4 = 0; dd4 < 16; dd4++){
      float w0 = ldsWT[(dd4*4+0)*32 + c2];
      float w1 = ldsWT[(dd4*4+1)*32 + c2];
      float w2 = ldsWT[(dd4*4+2)*32 + c2];
      float w3 = ldsWT[(dd4*4+3)*32 + c2];
      #pragma unroll
      for (int i = 0; i < 8; i++){
        int t = tl0 + 2*i;
        float4 yv = *(const float4*)&s_y[t][dd4*4];
        acc[i] += yv.x*w0 + yv.y*w1 + yv.z*w2 + yv.w*w3;
      }
    }
    #pragma unroll
    for (int i = 0; i < 8; i++){
      int tok = blockIdx.x*64 + tl0 + 2*i;
      int pix = tok >> 2, l = tok & 3;
      y2[(size_t)pix*128 + l*32 + c2] = acc[i];
      float s1 = acc[i], s2 = acc[i]*acc[i];
      s1 += __shfl_xor(s1,1);  s2 += __shfl_xor(s2,1);
      s1 += __shfl_xor(s1,2);  s2 += __shfl_xor(s2,2);
      s1 += __shfl_xor(s1,4);  s2 += __shfl_xor(s2,4);
      s1 += __shfl_xor(s1,8);  s2 += __shfl_xor(s2,8);
      s1 += __shfl_xor(s1,16); s2 += __shfl_xor(s2,16);
      if (c2 == 0){
        atomicAdd(&bst[l*2+0], s1);
        atomicAdd(&bst[l*2+1], s2);
      }
    }
  }
  __syncthreads();
  if (tid < 8) part[(size_t)blockIdx.x*8 + tid] = bst[tid];
}

// ---------------- fused fuse + dw: feat in LDS, logits + conv + GN partials --
// grid 256 = 2b x 16ty x 8tx; interior 4x8 pixels, halo 6x10.
__global__ void __launch_bounds__(256)
k_fusedw(const float* __restrict__ h1, const float* __restrict__ yproj,
         const float* __restrict__ y2, const float* __restrict__ partSPA,
         const float* __restrict__ partSPE,
         const float* __restrict__ spa_g, const float* __restrict__ spa_b,
         const float* __restrict__ spe_g, const float* __restrict__ spe_b,
         const float* __restrict__ fuse_w, const float* __restrict__ cls_w,
         const float* __restrict__ cls_b, const float* __restrict__ dww,
         float* __restrict__ logits, float* __restrict__ epre,
         float* __restrict__ part){
  __shared__ float ft[60*129];
  __shared__ float clsL[10*129];
  __shared__ float sst[32];
  __shared__ float red1[4][64], red2[4][64];
  int tid = threadIdx.x;
  reduce_part(partSPA, 256, sst);
  reduce_part(partSPE, 256, sst+16);
  for (int i = tid; i < 1280; i += 256){
    int o = i >> 7, cc = i & 127;
    clsL[o*129 + cc] = cls_w[o*128 + cc];
  }
  int blk = blockIdx.x;
  int b = blk >> 7, rem = blk & 127;
  int ty = rem >> 3, tx = rem & 7;
  int r0 = ty*4, c0 = tx*8;
  float e0 = __expf(fuse_w[0]), e1 = __expf(fuse_w[1]);
  float wA = e0/(e0+e1), wB = e1/(e0+e1);
  for (int idx = tid; idx < 7680; idx += 256){
    int pos = idx >> 7, c = idx & 127;
    int hr = pos/10, hc = pos - hr*10;
    int ry = r0 + hr - 1, rx = c0 + hc - 1;
    float f = 0.f;
    if (ry >= 0 && ry < 64 && rx >= 0 && rx < 64){
      size_t pix = (size_t)((b<<12)|(ry<<6)|rx);
      int g = c >> 5;
      float m1 = sst[b*8 + g*2]      * (1.f/NG);
      float v1 = sst[b*8 + g*2 + 1]  * (1.f/NG) - m1*m1;
      float m2 = sst[16 + b*8 + g*2] * (1.f/NG);
      float v2 = sst[16 + b*8 + g*2+1]*(1.f/NG) - m2*m2;
      float h = h1[pix*128 + c];
      float sa = siluf((yproj[pix*128+c]-m1)*rsqrtf(v1+1e-5f)*spa_g[c] + spa_b[c]) + h;
      float sp = h + siluf((y2[pix*128+c]-m2)*rsqrtf(v2+1e-5f)*spe_g[c] + spe_b[c]);
      f = sa*wA + sp*wB + h;
    }
    ft[pos*129 + c] = f;
  }
  __syncthreads();
  int c = tid & 127, pl = tid >> 7;
  float w9[9];
  #pragma unroll
  for (int k = 0; k < 9; k++) w9[k] = dww[c*9+k];
  float s1 = 0.f, s2 = 0.f;
  for (int i = 0; i < 16; i++){
    int px = i*2 + pl;
    int py = px >> 3, pxx = px & 7;
    float acc = 0.f;
    #pragma unroll
    for (int dy = 0; dy < 3; dy++)
      #pragma unroll
      for (int dx = 0; dx < 3; dx++)
        acc += ft[((py+dy)*10 + (pxx+dx))*129 + c] * w9[dy*3+dx];
    epre[(size_t)((b<<12)|((r0+py)<<6)|(c0+pxx))*128 + c] = acc;
    s1 += acc; s2 += acc*acc;
  }
  for (int idx = tid; idx < 320; idx += 256){
    int px = idx/10, o = idx - px*10;
    int py = px >> 3, pxx = px & 7;
    int pos = (py+1)*10 + (pxx+1);
    float acc = cls_b[o];
    for (int cc = 0; cc < 128; cc++)
      acc += ft[pos*129 + cc] * clsL[o*129 + cc];
    logits[(size_t)((b<<12)|((r0+py)<<6)|(c0+pxx))*16 + o] = acc;
  }
  int g = c >> 5;
  int ridx0 = (c & 31) | (pl << 5);
  red1[g][ridx0] = s1; red2[g][ridx0] = s2;
  __syncthreads();
  int rg = tid >> 6, ridx = tid & 63;
  for (int s = 32; s >= 1; s >>= 1){
    if (ridx < s){ red1[rg][ridx] += red1[rg][ridx+s]; red2[rg][ridx] += red2[rg][ridx+s]; }
    __syncthreads();
  }
  if (ridx == 0){
    part[(size_t)blk*8 + rg*2+0] = red1[rg][0];
    part[(size_t)blk*8 + rg*2+1] = red2[rg][0];
  }
}

// ---------------- final: inline ref-stats reduce + edge + local avg ----------
__global__ void __launch_bounds__(256)
k_final(const float* __restrict__ epre, const float* __restrict__ logits,
        const float* __restrict__ partDW, const float* __restrict__ rg_g,
        const float* __restrict__ rg_b, const float* __restrict__ pw_w,
        const float* __restrict__ pw_b, const float* __restrict__ alpha,
        float* __restrict__ outp){
  __shared__ float sst[16];
  __shared__ float part[4];
  __shared__ float edge_s[2];
  reduce_part(partDW, 128, sst);
  int tid = threadIdx.x;
  int pixl = tid >> 7, c = tid & 127;
  int pix = blockIdx.x*2 + pixl;
  int b = pix >> 12, p = pix & 4095, yy = p >> 6, xx = p & 63;
  int g = c >> 5;
  float m = sst[b*8 + g*2]   * (1.f/NG);
  float v = sst[b*8 + g*2+1] * (1.f/NG) - m*m;
  float e = epre[(size_t)pix*128+c];
  float en = siluf((e-m)*rsqrtf(v+1e-5f)*rg_g[c] + rg_b[c]);
  float pv = en * pw_w[c];
  pv += __shfl_xor(pv,1);  pv += __shfl_xor(pv,2);  pv += __shfl_xor(pv,4);
  pv += __shfl_xor(pv,8);  pv += __shfl_xor(pv,16); pv += __shfl_xor(pv,32);
  if ((tid & 63) == 0) part[tid>>6] = pv;
  __syncthreads();
  if (tid < 2) edge_s[tid] = sigm(part[tid*2] + part[tid*2+1] + pw_b[0]);
  __syncthreads();
  if (c < 10){
    float ed = edge_s[pixl];
    int o = c;
    float lg = logits[(size_t)pix*16 + o];
    float loc = 0.f;
    for (int dy = -1; dy <= 1; dy++){
      int ny = yy+dy; if (ny < 0 || ny > 63) continue;
      for (int dx = -1; dx <= 1; dx++){
        int nx = xx+dx; if (nx < 0 || nx > 63) continue;
        loc += logits[(size_t)((b<<12)|(ny<<6)|nx)*16 + o];
      }
    }
    loc *= (1.f/9.f);
    outp[(size_t)((b*10+o)<<12) + p] = lg + alpha[0]*(1.f-ed)*(loc - lg);
  }
}

extern "C" void kernel_launch(void* const* d_in, const int* in_sizes, int n_in,
                              void* d_out, int out_size, void* d_ws, size_t ws_size,
                              hipStream_t stream){
  const float* x          = (const float*)d_in[0];
  const float* pe_w       = (const float*)d_in[1];
  const float* pe_b       = (const float*)d_in[2];
  const float* pe_gn_g    = (const float*)d_in[3];
  const float* pe_gn_b    = (const float*)d_in[4];
  const float* spa_in_w   = (const float*)d_in[5];
  const float* spa_conv_w = (const float*)d_in[6];
  const float* spa_conv_b = (const float*)d_in[7];
  const float* spa_xproj_w= (const float*)d_in[8];
  const float* spa_dt_w   = (const float*)d_in[9];
  const float* spa_dt_b   = (const float*)d_in[10];
  const float* spa_Alog   = (const float*)d_in[11];
  const float* spa_D      = (const float*)d_in[12];
  const float* spa_out_w  = (const float*)d_in[13];
  const float* spa_gn_g   = (const float*)d_in[14];
  const float* spa_gn_b   = (const float*)d_in[15];
  const float* spe_in_w   = (const float*)d_in[16];
  const float* spe_conv_w = (const float*)d_in[17];
  const float* spe_conv_b = (const float*)d_in[18];
  const float* spe_xproj_w= (const float*)d_in[19];
  const float* spe_dt_w   = (const float*)d_in[20];
  const float* spe_dt_b   = (const float*)d_in[21];
  const float* spe_Alog   = (const float*)d_in[22];
  const float* spe_D      = (const float*)d_in[23];
  const float* spe_out_w  = (const float*)d_in[24];
  const float* spe_gn_g   = (const float*)d_in[25];
  const float* spe_gn_b   = (const float*)d_in[26];
  const float* fuse_w     = (const float*)d_in[27];
  const float* cls_w      = (const float*)d_in[28];
  const float* cls_b      = (const float*)d_in[29];
  const float* ref_dw_w   = (const float*)d_in[30];
  const float* ref_gn_g   = (const float*)d_in[31];
  const float* ref_gn_b   = (const float*)d_in[32];
  const float* ref_pw_w   = (const float*)d_in[33];
  const float* ref_pw_b   = (const float*)d_in[34];
  const float* alpha      = (const float*)d_in[35];
  float* ws  = (float*)d_ws;
  float* out = (float*)d_out;

  float* Pb    = ws + WS_POFF;   // hs aliases Pb (scan2 in-place)
  float* Qb    = ws + WS_QOFF;   // Q dead after scan2 (proj2/logits written later)
  float* HSb   = Pb;
  float* dely  = ws + WS_Y;      // delta; scan3 writes y over it
  float* partPE  = ws + WS_Y;          // consumed by k_xz before k_projc overwrites
  float* partSPA = ws + WS_POFF;       // hs dead after scan3
  float* partSPE = ws + WS_POFF + 16384;
  float* partDW  = ws + WS_POFF + 65536;
  float* proj  = ws + WS_PROJ;
  float* xc2   = ws + WS_XC;           // xc dead after scan3
  float* zsil2 = ws + WS_XZD;          // xzd dead after projc
  float* proj2 = ws + WS_QOFF;         // Q dead after scan2
  float* epre  = ws + WS_Y;            // y dead after outproj

  k_pe<<<dim3(2,256),256,0,stream>>>(x, pe_w, pe_b, ws+WS_H1PRE, partPE);
  k_xz<<<dim3(8,128),256,0,stream>>>(ws+WS_H1PRE, spa_in_w, partPE,
      pe_gn_g, pe_gn_b, ws+WS_H1, ws+WS_XZD, ws+WS_ZSIL);
  k_projc<<<512,256,0,stream>>>(ws+WS_XZD, spa_conv_w, spa_conv_b, spa_xproj_w,
      spa_dt_w, spa_dt_b, ws+WS_XC, proj, dely);
  k_scan1<<<2048,256,0,stream>>>(dely, proj, ws+WS_XC, spa_Alog, Pb, Qb);
  k_scan2<<<512,256,0,stream>>>(Pb, Qb, HSb);
  k_scan3<<<2048,256,0,stream>>>(dely, proj, ws+WS_XC, ws+WS_ZSIL,
      spa_Alog, spa_D, HSb, dely);
  k_outproj<<<dim3(2,256),256,0,stream>>>(dely, spa_out_w, ws+WS_H1PRE, partSPA);
  k_spe_ab<<<512,256,0,stream>>>(ws+WS_H1, spe_in_w, spe_conv_w, spe_conv_b,
      spe_xproj_w, xc2, zsil2, proj2);
  k_spe_cd<<<512,256,0,stream>>>(xc2, zsil2, proj2, spe_dt_w, spe_dt_b,
      spe_Alog, spe_D, spe_out_w, ws+WS_Y2, partSPE);
  k_fusedw<<<256,256,0,stream>>>(ws+WS_H1, ws+WS_H1PRE, ws+WS_Y2,
      partSPA, partSPE, spa_gn_g, spa_gn_b, spe_gn_g, spe_gn_b,
      fuse_w, cls_w, cls_b, ref_dw_w, ws+WS_LOG, epre, partDW);
  k_final<<<4096,256,0,stream>>>(epre, ws+WS_LOG, partDW,
      ref_gn_g, ref_gn_b, ref_pw_w, ref_pw_b, alpha, out);
  (void)in_sizes; (void)n_in; (void)out_size; (void)ws_size;
}

// Round 15
// 372.438 us; speedup vs baseline: 1.0547x; 1.0177x over previous
//
#include <hip/hip_runtime.h>
#include <math.h>

#define DEV __device__ __forceinline__

DEV float sigm(float x){ return 1.f/(1.f+__expf(-x)); }
DEV float siluf(float x){ return x * sigm(x); }
DEV float softplusf(float x){ return x > 20.f ? x : log1pf(__expf(x)); }

static constexpr float NG = 131072.0f;   // group-norm element count per (b,g)
static constexpr float LOG2E = 1.4426950408889634f;

// ---- workspace layout (offsets in floats) ----
static constexpr size_t WS_H1    = 0;          // B*HW*128
static constexpr size_t WS_H1PRE = 1048576;    // h1pre; later yproj
static constexpr size_t WS_XC    = 2097152;    // spa xc; later spe xc2
static constexpr size_t WS_ZSIL  = 4194304;    // spa zsil
static constexpr size_t WS_XZD   = 6291456;    // dense xzd [8192][256] (2M); later spe zsil2
static constexpr size_t WS_QOFF  = 8388608;    // scan Q (2M); later proj2/logits (after scan2)
static constexpr size_t WS_LOG   = 8650752;    // logits (k_fusedw; Q/proj2 dead by then)
static constexpr size_t WS_Y     = 10485760;   // partPE; delta/y; spe yg; later epre
static constexpr size_t WS_POFF  = 12582912;   // scan P / hs (2M); after scan3: partials
static constexpr size_t WS_Y2    = 14155776;   // B*HW*128 (spe_d; hs dead)
static constexpr size_t WS_PROJ  = 15204352;   // proj[8192][40]

// ---- in-kernel partial reduce: part[b*rowsPerB+row][8] -> dst16[16] ----
DEV void reduce_part(const float* __restrict__ part, int rowsPerB, float* dst16){
  int tid = threadIdx.x;
  int p = tid >> 4, sl = tid & 15;      // p = b*8 + j
  int b = p >> 3, j = p & 7;
  float s = 0.f;
  for (int row = sl; row < rowsPerB; row += 16)
    s += part[((size_t)b*rowsPerB + row)*8 + j];
  s += __shfl_xor(s,1); s += __shfl_xor(s,2);
  s += __shfl_xor(s,4); s += __shfl_xor(s,8);
  if (sl == 0) dst16[p] = s;
  __syncthreads();
}

// ---------------- pe 1x1 conv (tiled GEMM 32x64) + GN partials ---------------
__global__ void __launch_bounds__(256)
k_pe(const float* __restrict__ x, const float* __restrict__ pe_w,
     const float* __restrict__ pe_b, float* __restrict__ h1pre,
     float* __restrict__ part){
  __shared__ float As[16][36];
  __shared__ float Bs[16][64];
  __shared__ float red1[2][4], red2[2][4];
  int tid = threadIdx.x;
  int nx = blockIdx.x, my = blockIdx.y;
  int m0 = my*32, n0 = nx*64;
  int b = m0 >> 12, pl0 = m0 & 4095;
  int tx = tid & 15, ty = tid >> 4;
  float acc[2][4];
  #pragma unroll
  for (int i = 0; i < 2; i++)
    #pragma unroll
    for (int j = 0; j < 4; j++) acc[i][j] = 0.f;
  for (int k0 = 0; k0 < 128; k0 += 16){
    if (tid < 128){
      int k = tid >> 3, mm = (tid & 7)*4;
      float4 a = *(const float4*)(x + ((size_t)b*128 + k0+k)*4096 + pl0 + mm);
      *(float4*)&As[k][mm] = a;
    }
    {
      int n = tid >> 2, kq = (tid & 3)*4;
      float4 a = *(const float4*)(pe_w + (size_t)(n0+n)*128 + k0 + kq);
      Bs[kq+0][n] = a.x; Bs[kq+1][n] = a.y; Bs[kq+2][n] = a.z; Bs[kq+3][n] = a.w;
    }
    __syncthreads();
    #pragma unroll
    for (int k = 0; k < 16; k++){
      float2 av = *(const float2*)&As[k][ty*2];
      float4 bv = *(const float4*)&Bs[k][tx*4];
      acc[0][0] += av.x*bv.x; acc[0][1] += av.x*bv.y; acc[0][2] += av.x*bv.z; acc[0][3] += av.x*bv.w;
      acc[1][0] += av.y*bv.x; acc[1][1] += av.y*bv.y; acc[1][2] += av.y*bv.z; acc[1][3] += av.y*bv.w;
    }
    __syncthreads();
  }
  float4 bias = *(const float4*)(pe_b + n0 + tx*4);
  float s1 = 0.f, s2 = 0.f;
  #pragma unroll
  for (int i = 0; i < 2; i++){
    float4 st;
    st.x = acc[i][0]+bias.x; st.y = acc[i][1]+bias.y;
    st.z = acc[i][2]+bias.z; st.w = acc[i][3]+bias.w;
    s1 += st.x+st.y+st.z+st.w;
    s2 += st.x*st.x + st.y*st.y + st.z*st.z + st.w*st.w;
    *(float4*)(h1pre + (size_t)(m0 + ty*2 + i)*128 + n0 + tx*4) = st;
  }
  s1 += __shfl_xor(s1,1);  s2 += __shfl_xor(s2,1);
  s1 += __shfl_xor(s1,2);  s2 += __shfl_xor(s2,2);
  s1 += __shfl_xor(s1,4);  s2 += __shfl_xor(s2,4);
  s1 += __shfl_xor(s1,16); s2 += __shfl_xor(s2,16);
  s1 += __shfl_xor(s1,32); s2 += __shfl_xor(s2,32);
  int lane = tid & 63, w = tid >> 6;
  if ((lane & 55) == 0){
    int gl = (lane >> 3) & 1;
    red1[gl][w] = s1; red2[gl][w] = s2;
  }
  __syncthreads();
  if (tid < 8){
    int gg = tid >> 1, which = tid & 1;
    int gl = gg - nx*2;
    float v = 0.f;
    if (gl == 0 || gl == 1){
      v = which ? (red2[gl][0]+red2[gl][1]+red2[gl][2]+red2[gl][3])
                : (red1[gl][0]+red1[gl][1]+red1[gl][2]+red1[gl][3]);
    }
    int pblk = b*256 + (my & 127)*2 + nx;
    part[(size_t)pblk*8 + tid] = v;
  }
}

// ---------------- spa in-proj GEMM 64x64, inline pe-stats + GN+silu ----------
__global__ void __launch_bounds__(256)
k_xz(const float* __restrict__ h1pre, const float* __restrict__ in_w,
     const float* __restrict__ partPE, const float* __restrict__ gng,
     const float* __restrict__ gnb, float* __restrict__ h1,
     float* __restrict__ xzd, float* __restrict__ zsil){
  __shared__ float As[16][68];
  __shared__ float Bs[16][64];
  __shared__ float sst[16];
  reduce_part(partPE, 256, sst);
  int tid = threadIdx.x;
  int m0 = blockIdx.y*64, n0 = blockIdx.x*64;
  int tx = tid & 15, ty = tid >> 4;
  float acc[4][4];
  #pragma unroll
  for (int i = 0; i < 4; i++)
    #pragma unroll
    for (int j = 0; j < 4; j++) acc[i][j] = 0.f;
  for (int k0 = 0; k0 < 128; k0 += 16){
    {
      int m = tid >> 2, kk = (tid & 3)*4;
      int pixm = m0 + m, c0 = k0 + kk;
      int bb = pixm >> 12, g = c0 >> 5;
      float4 a = *(const float4*)(h1pre + (size_t)pixm*128 + c0);
      float mu = sst[bb*8 + g*2] * (1.f/NG);
      float var = sst[bb*8 + g*2 + 1] * (1.f/NG) - mu*mu;
      float rs = rsqrtf(var + 1e-5f);
      float4 gg = *(const float4*)(gng + c0);
      float4 gb = *(const float4*)(gnb + c0);
      float4 v;
      v.x = siluf((a.x-mu)*rs*gg.x + gb.x);
      v.y = siluf((a.y-mu)*rs*gg.y + gb.y);
      v.z = siluf((a.z-mu)*rs*gg.z + gb.z);
      v.w = siluf((a.w-mu)*rs*gg.w + gb.w);
      As[kk+0][m] = v.x; As[kk+1][m] = v.y; As[kk+2][m] = v.z; As[kk+3][m] = v.w;
      if (blockIdx.x == 0) *(float4*)(h1 + (size_t)pixm*128 + c0) = v;
    }
    {
      int n = tid >> 2, kq = (tid & 3)*4;
      float4 a = *(const float4*)(in_w + (size_t)(n0+n)*128 + k0 + kq);
      Bs[kq+0][n] = a.x; Bs[kq+1][n] = a.y; Bs[kq+2][n] = a.z; Bs[kq+3][n] = a.w;
    }
    __syncthreads();
    #pragma unroll
    for (int k = 0; k < 16; k++){
      float4 av = *(const float4*)&As[k][ty*4];
      float4 bv = *(const float4*)&Bs[k][tx*4];
      acc[0][0] += av.x*bv.x; acc[0][1] += av.x*bv.y; acc[0][2] += av.x*bv.z; acc[0][3] += av.x*bv.w;
      acc[1][0] += av.y*bv.x; acc[1][1] += av.y*bv.y; acc[1][2] += av.y*bv.z; acc[1][3] += av.y*bv.w;
      acc[2][0] += av.z*bv.x; acc[2][1] += av.z*bv.y; acc[2][2] += av.z*bv.z; acc[2][3] += av.z*bv.w;
      acc[3][0] += av.w*bv.x; acc[3][1] += av.w*bv.y; acc[3][2] += av.w*bv.z; acc[3][3] += av.w*bv.w;
    }
    __syncthreads();
  }
  if (n0 < 256){
    #pragma unroll
    for (int i = 0; i < 4; i++){
      float4 st; st.x = acc[i][0]; st.y = acc[i][1]; st.z = acc[i][2]; st.w = acc[i][3];
      *(float4*)(xzd + (size_t)(m0 + ty*4 + i)*256 + n0 + tx*4) = st;
    }
  } else {
    #pragma unroll
    for (int i = 0; i < 4; i++){
      float4 st;
      st.x = siluf(acc[i][0]); st.y = siluf(acc[i][1]);
      st.z = siluf(acc[i][2]); st.w = siluf(acc[i][3]);
      *(float4*)(zsil + (size_t)(m0 + ty*4 + i)*256 + (n0-256) + tx*4) = st;
    }
  }
}

// ---------------- fused conv + x-proj + delta ----------------
__global__ void __launch_bounds__(256)
k_projc(const float* __restrict__ xzd, const float* __restrict__ cw,
        const float* __restrict__ cb, const float* __restrict__ xpw,
        const float* __restrict__ dtw, const float* __restrict__ dtb,
        float* __restrict__ xc, float* __restrict__ proj,
        float* __restrict__ delta){
  __shared__ float xct[16*260];
  __shared__ float s_dt[16][9];
  int tid = threadIdx.x;
  int m0 = blockIdx.x * 16;
  {
    int slot = tid >> 6, lane = tid & 63;
    int d4 = lane*4;
    float4 cbv = *(const float4*)(cb + d4);
    float4 cw0 = *(const float4*)(cw + (size_t)(d4+0)*4);
    float4 cw1 = *(const float4*)(cw + (size_t)(d4+1)*4);
    float4 cw2 = *(const float4*)(cw + (size_t)(d4+2)*4);
    float4 cw3 = *(const float4*)(cw + (size_t)(d4+3)*4);
    const float* c0p = (const float*)&cw0;
    const float* c1p = (const float*)&cw1;
    const float* c2p = (const float*)&cw2;
    const float* c3p = (const float*)&cw3;
    for (int i = 0; i < 4; i++){
      int t = slot*4 + i;
      int tok = m0 + t;
      int l = tok & 4095;
      float4 acc = cbv;
      #pragma unroll
      for (int k = 0; k < 4; k++){
        int ls = l - 3 + k;
        if (ls >= 0){
          float4 xv = *(const float4*)(xzd + (size_t)(tok-3+k)*256 + d4);
          acc.x += xv.x * c0p[k];
          acc.y += xv.y * c1p[k];
          acc.z += xv.z * c2p[k];
          acc.w += xv.w * c3p[k];
        }
      }
      float4 s;
      s.x = siluf(acc.x); s.y = siluf(acc.y); s.z = siluf(acc.z); s.w = siluf(acc.w);
      *(float4*)&xct[t*260 + d4] = s;
      *(float4*)(xc + (size_t)tok*256 + d4) = s;
    }
  }
  __syncthreads();
  {
    int t = tid & 15, jq = tid >> 4;
    int tok = m0 + t;
    float a0 = 0.f, a1 = 0.f, a2 = 0.f;
    for (int k0 = 0; k0 < 256; k0 += 4){
      float4 av = *(const float4*)&xct[t*260 + k0];
      float4 w0 = *(const float4*)(xpw + (size_t)jq*256 + k0);
      float4 w1 = *(const float4*)(xpw + (size_t)(jq+16)*256 + k0);
      a0 += av.x*w0.x + av.y*w0.y + av.z*w0.z + av.w*w0.w;
      a1 += av.x*w1.x + av.y*w1.y + av.z*w1.z + av.w*w1.w;
      if (jq < 8){
        float4 w2 = *(const float4*)(xpw + (size_t)(jq+32)*256 + k0);
        a2 += av.x*w2.x + av.y*w2.y + av.z*w2.z + av.w*w2.w;
      }
    }
    float* pr = proj + (size_t)tok*40;
    pr[jq] = a0;
    pr[jq+16] = a1;
    if (jq < 8){ pr[jq+32] = a2; s_dt[t][jq] = a0; }
  }
  __syncthreads();
  {
    int d = tid;
    const float4* wr = (const float4*)(dtw + (size_t)d*8);
    float4 w0 = wr[0], w1 = wr[1];
    float bd = dtb[d];
    for (int t = 0; t < 16; t++){
      float v = bd + s_dt[t][0]*w0.x + s_dt[t][1]*w0.y + s_dt[t][2]*w0.z + s_dt[t][3]*w0.w
                   + s_dt[t][4]*w1.x + s_dt[t][5]*w1.y + s_dt[t][6]*w1.z + s_dt[t][7]*w1.w;
      delta[(size_t)(m0+t)*256 + d] = softplusf(v);
    }
  }
}

// ---------------- scan phase 1: thread=(d, n-quartet), 16-step chunks --------
__global__ void __launch_bounds__(256)
k_scan1(const float* __restrict__ delta, const float* __restrict__ proj,
        const float* __restrict__ xc, const float* __restrict__ Alog,
        float* __restrict__ P, float* __restrict__ Q){
  int blk = blockIdx.x;
  int dblk = blk & 3;
  int bc = blk >> 2;
  int b = bc >> 8, chunk = bc & 255;
  int tid = threadIdx.x;
  int dl = tid >> 2, ng = tid & 3;
  int d = dblk*64 + dl;
  float4 a4 = *(const float4*)(Alog + (size_t)d*16 + ng*4);
  float An[4] = {-__expf(a4.x)*LOG2E, -__expf(a4.y)*LOG2E,
                 -__expf(a4.z)*LOG2E, -__expf(a4.w)*LOG2E};
  float Pv[4] = {1.f,1.f,1.f,1.f}, Qv[4] = {0.f,0.f,0.f,0.f};
  size_t row0 = (size_t)(b*4096 + chunk*16);
  for (int l = 0; l < 16; l++){
    size_t r = row0 + l;
    float dv = delta[r*256 + d];
    float xv = xc[r*256 + d];
    float4 bm = *(const float4*)(proj + r*40 + 8 + ng*4);
    float dBx = dv*xv;
    float bmv[4] = {bm.x, bm.y, bm.z, bm.w};
    #pragma unroll
    for (int k = 0; k < 4; k++){
      float a = exp2f(dv*An[k]);
      Qv[k] = a*Qv[k] + bmv[k]*dBx;
      Pv[k] *= a;
    }
  }
  size_t o = (size_t)bc*4096 + dblk*1024 + tid*4;
  float4 pv; pv.x=Pv[0]; pv.y=Pv[1]; pv.z=Pv[2]; pv.w=Pv[3];
  float4 qv; qv.x=Qv[0]; qv.y=Qv[1]; qv.z=Qv[2]; qv.w=Qv[3];
  *(float4*)(P + o) = pv;
  *(float4*)(Q + o) = qv;
}

// ---------------- scan phase 2: 256-chunk scan; lane owns 4 chunks -----------
__global__ void __launch_bounds__(256)
k_scan2(const float* __restrict__ P, const float* __restrict__ Q,
        float* __restrict__ hs){
  __shared__ float Ps[256][17], Qs[256][17];
  int tid = threadIdx.x;
  int b = blockIdx.x >> 8;
  int dn0 = (blockIdx.x & 255) * 16;
  for (int i = tid; i < 1024; i += 256){
    int ch = i >> 2, g = (i & 3)*4;
    size_t gaddr = (size_t)(b*256+ch)*4096 + dn0 + g;
    float4 p = *(const float4*)(P + gaddr);
    float4 q = *(const float4*)(Q + gaddr);
    Ps[ch][g]=p.x; Ps[ch][g+1]=p.y; Ps[ch][g+2]=p.z; Ps[ch][g+3]=p.w;
    Qs[ch][g]=q.x; Qs[ch][g+1]=q.y; Qs[ch][g+2]=q.z; Qs[ch][g+3]=q.w;
  }
  __syncthreads();
  int lane = tid & 63, wv = tid >> 6;
  for (int rep = 0; rep < 4; rep++){
    int c = wv*4 + rep;
    float p0 = Ps[4*lane+0][c], q0 = Qs[4*lane+0][c];
    float p1 = Ps[4*lane+1][c], q1 = Qs[4*lane+1][c];
    float p2 = Ps[4*lane+2][c], q2 = Qs[4*lane+2][c];
    float p3 = Ps[4*lane+3][c], q3 = Qs[4*lane+3][c];
    float p = p0, q = q0;
    q = p1*q + q1; p *= p1;
    q = p2*q + q2; p *= p2;
    q = p3*q + q3; p *= p3;
    #pragma unroll
    for (int off = 1; off < 64; off <<= 1){
      float pp = __shfl_up(p, off);
      float qp = __shfl_up(q, off);
      if (lane >= off){ q = p*qp + q; p = p*pp; }
    }
    float h0 = __shfl_up(q, 1);
    if (lane == 0) h0 = 0.f;
    float h1 = p0*h0 + q0;
    float h2 = p1*h1 + q1;
    float h3 = p2*h2 + q2;
    Ps[4*lane+0][c] = h0;
    Ps[4*lane+1][c] = h1;
    Ps[4*lane+2][c] = h2;
    Ps[4*lane+3][c] = h3;
  }
  __syncthreads();
  for (int i = tid; i < 1024; i += 256){
    int ch = i >> 2, g = (i & 3)*4;
    size_t gaddr = (size_t)(b*256+ch)*4096 + dn0 + g;
    float4 h;
    h.x = Ps[ch][g]; h.y = Ps[ch][g+1]; h.z = Ps[ch][g+2]; h.w = Ps[ch][g+3];
    *(float4*)(hs + gaddr) = h;
  }
}

// ---------------- scan phase 3: replay + y; thread=(d, n-quartet) ------------
__global__ void __launch_bounds__(256)
k_scan3(const float* __restrict__ delta, const float* __restrict__ proj,
        const float* __restrict__ xc, const float* __restrict__ zsil,
        const float* __restrict__ Alog, const float* __restrict__ Dv,
        const float* __restrict__ hs, float* __restrict__ y){
  int blk = blockIdx.x;
  int dblk = blk & 3;
  int bc = blk >> 2;
  int b = bc >> 8, chunk = bc & 255;
  int tid = threadIdx.x;
  int dl = tid >> 2, ng = tid & 3;
  int d = dblk*64 + dl;
  float4 a4 = *(const float4*)(Alog + (size_t)d*16 + ng*4);
  float An[4] = {-__expf(a4.x)*LOG2E, -__expf(a4.y)*LOG2E,
                 -__expf(a4.z)*LOG2E, -__expf(a4.w)*LOG2E};
  float Dd = Dv[d];
  float h[4];
  {
    size_t o = (size_t)bc*4096 + dblk*1024 + tid*4;
    float4 hv = *(const float4*)(hs + o);
    h[0]=hv.x; h[1]=hv.y; h[2]=hv.z; h[3]=hv.w;
  }
  size_t row0 = (size_t)(b*4096 + chunk*16);
  for (int l = 0; l < 16; l++){
    size_t r = row0 + l;
    float dv = delta[r*256 + d];
    float xv = xc[r*256 + d];
    float4 bm = *(const float4*)(proj + r*40 + 8 + ng*4);
    float4 cm = *(const float4*)(proj + r*40 + 24 + ng*4);
    float dBx = dv*xv;
    float bmv[4] = {bm.x, bm.y, bm.z, bm.w};
    float cmv[4] = {cm.x, cm.y, cm.z, cm.w};
    float ys = 0.f;
    #pragma unroll
    for (int k = 0; k < 4; k++){
      float a = exp2f(dv*An[k]);
      h[k] = a*h[k] + bmv[k]*dBx;
      ys += h[k]*cmv[k];
    }
    ys += __shfl_xor(ys, 1);
    ys += __shfl_xor(ys, 2);
    if (ng == 0){
      float zv = zsil[r*256 + d];
      y[r*256 + d] = (ys + Dd*xv) * zv;
    }
  }
}

// ---------------- spa out-proj: tiled GEMM 32x64 + GN partials ---------------
__global__ void __launch_bounds__(256)
k_outproj(const float* __restrict__ y, const float* __restrict__ out_w,
          float* __restrict__ yproj, float* __restrict__ part){
  __shared__ float As[16][36];
  __shared__ float Bs[16][64];
  __shared__ float red1[2][4], red2[2][4];
  int tid = threadIdx.x;
  int nx = blockIdx.x, my = blockIdx.y;
  int m0 = my*32, n0 = nx*64;
  int b = m0 >> 12;
  int tx = tid & 15, ty = tid >> 4;
  float acc[2][4];
  #pragma unroll
  for (int i = 0; i < 2; i++)
    #pragma unroll
    for (int j = 0; j < 4; j++) acc[i][j] = 0.f;
  for (int k0 = 0; k0 < 256; k0 += 16){
    if (tid < 128){
      int m = tid >> 2, kk = (tid & 3)*4;
      float4 a = *(const float4*)(y + (size_t)(m0+m)*256 + k0+kk);
      As[kk+0][m] = a.x; As[kk+1][m] = a.y; As[kk+2][m] = a.z; As[kk+3][m] = a.w;
    }
    {
      int n = tid >> 2, kq = (tid & 3)*4;
      float4 a = *(const float4*)(out_w + (size_t)(n0+n)*256 + k0 + kq);
      Bs[kq+0][n] = a.x; Bs[kq+1][n] = a.y; Bs[kq+2][n] = a.z; Bs[kq+3][n] = a.w;
    }
    __syncthreads();
    #pragma unroll
    for (int k = 0; k < 16; k++){
      float2 av = *(const float2*)&As[k][ty*2];
      float4 bv = *(const float4*)&Bs[k][tx*4];
      acc[0][0] += av.x*bv.x; acc[0][1] += av.x*bv.y; acc[0][2] += av.x*bv.z; acc[0][3] += av.x*bv.w;
      acc[1][0] += av.y*bv.x; acc[1][1] += av.y*bv.y; acc[1][2] += av.y*bv.z; acc[1][3] += av.y*bv.w;
    }
    __syncthreads();
  }
  float s1 = 0.f, s2 = 0.f;
  #pragma unroll
  for (int i = 0; i < 2; i++){
    float4 st; st.x = acc[i][0]; st.y = acc[i][1]; st.z = acc[i][2]; st.w = acc[i][3];
    s1 += st.x+st.y+st.z+st.w;
    s2 += st.x*st.x + st.y*st.y + st.z*st.z + st.w*st.w;
    *(float4*)(yproj + (size_t)(m0 + ty*2 + i)*128 + n0 + tx*4) = st;
  }
  s1 += __shfl_xor(s1,1);  s2 += __shfl_xor(s2,1);
  s1 += __shfl_xor(s1,2);  s2 += __shfl_xor(s2,2);
  s1 += __shfl_xor(s1,4);  s2 += __shfl_xor(s2,4);
  s1 += __shfl_xor(s1,16); s2 += __shfl_xor(s2,16);
  s1 += __shfl_xor(s1,32); s2 += __shfl_xor(s2,32);
  int lane = tid & 63, w = tid >> 6;
  if ((lane & 55) == 0){
    int gl = (lane >> 3) & 1;
    red1[gl][w] = s1; red2[gl][w] = s2;
  }
  __syncthreads();
  if (tid < 8){
    int gg = tid >> 1, which = tid & 1;
    int gl = gg - nx*2;
    float v = 0.f;
    if (gl == 0 || gl == 1){
      v = which ? (red2[gl][0]+red2[gl][1]+red2[gl][2]+red2[gl][3])
                : (red1[gl][0]+red1[gl][1]+red1[gl][2]+red1[gl][3]);
    }
    int pblk = b*256 + (my & 127)*2 + nx;
    part[(size_t)pblk*8 + tid] = v;
  }
}

// ---------------- spe A+B: in-proj + conv + silu + x-proj --------------------
__global__ void __launch_bounds__(256)
k_spe_ab(const float* __restrict__ h1, const float* __restrict__ in_w,
         const float* __restrict__ conv_w, const float* __restrict__ conv_b,
         const float* __restrict__ xpw, float* __restrict__ xc2,
         float* __restrict__ zsil2, float* __restrict__ proj2){
  __shared__ float s_in[4][128];
  __shared__ float s_xc[64][66];
  int tid = threadIdx.x;
  int w = tid >> 6, lane = tid & 63;
  {
    float wx[32], wz[32];
    const float4* rx = (const float4*)(in_w + (size_t)lane*32);
    const float4* rz = (const float4*)(in_w + (size_t)(64+lane)*32);
    #pragma unroll
    for (int k = 0; k < 8; k++){
      float4 a = rx[k]; wx[k*4]=a.x; wx[k*4+1]=a.y; wx[k*4+2]=a.z; wx[k*4+3]=a.w;
      float4 b = rz[k]; wz[k*4]=b.x; wz[k*4+1]=b.y; wz[k*4+2]=b.z; wz[k*4+3]=b.w;
    }
    float4 cwv = ((const float4*)conv_w)[lane];
    float cbv = conv_b[lane];
    for (int i = 0; i < 4; i++){
      int pix = blockIdx.x*16 + w*4 + i;
      float2 hv = ((const float2*)(h1 + (size_t)pix*128))[lane];
      s_in[w][2*lane] = hv.x; s_in[w][2*lane+1] = hv.y;
      float xpr[4], zs[4];
      #pragma unroll
      for (int l = 0; l < 4; l++){
        const float4* sv = (const float4*)&s_in[w][l*32];
        float ax = 0.f, az = 0.f;
        #pragma unroll
        for (int c4 = 0; c4 < 8; c4++){
          float4 v = sv[c4];
          ax += v.x*wx[c4*4] + v.y*wx[c4*4+1] + v.z*wx[c4*4+2] + v.w*wx[c4*4+3];
          az += v.x*wz[c4*4] + v.y*wz[c4*4+1] + v.z*wz[c4*4+2] + v.w*wz[c4*4+3];
        }
        xpr[l] = ax; zs[l] = siluf(az);
      }
      #pragma unroll
      for (int l = 0; l < 4; l++){
        float v = cbv;
        if (l >= 3) v += xpr[l-3]*cwv.x;
        if (l >= 2) v += xpr[l-2]*cwv.y;
        if (l >= 1) v += xpr[l-1]*cwv.z;
        v += xpr[l]*cwv.w;
        float sx = siluf(v);
        int t = (w*4+i)*4 + l;
        int tok = blockIdx.x*64 + t;
        s_xc[t][lane] = sx;
        xc2 [(size_t)tok*64 + lane] = sx;
        zsil2[(size_t)tok*64 + lane] = zs[l];
      }
    }
  }
  __syncthreads();
  {
    int t = lane;
    float a[9];
    #pragma unroll
    for (int j = 0; j < 9; j++) a[j] = 0.f;
    for (int k = 0; k < 64; k++){
      float xk = s_xc[t][k];
      #pragma unroll
      for (int j = 0; j < 9; j++){
        int ja = w*9 + j; if (ja > 33) ja = 33;
        a[j] += xk * xpw[(size_t)ja*64 + k];
      }
    }
    float* pr = proj2 + (size_t)(blockIdx.x*64 + t)*36;
    #pragma unroll
    for (int j = 0; j < 9; j++){
      int ja = w*9 + j;
      if (ja < 34) pr[ja] = a[j];
    }
  }
}

// ---------------- spe C: delta + scan + gate (lane=d, 4 pixels/wave) ---------
__global__ void __launch_bounds__(256)
k_spe_c(const float* __restrict__ xc2, const float* __restrict__ zsil2,
        const float* __restrict__ proj, const float* __restrict__ dt_w,
        const float* __restrict__ dt_b, const float* __restrict__ Alog,
        const float* __restrict__ Dvec, float* __restrict__ yg){
  int tid = threadIdx.x;
  int w = tid >> 6, lane = tid & 63;
  float2 dtwv = ((const float2*)dt_w)[lane];
  float dbv = dt_b[lane], Dd = Dvec[lane];
  float An[16];
  {
    const float4* ar = (const float4*)(Alog + (size_t)lane*16);
    #pragma unroll
    for (int k = 0; k < 4; k++){
      float4 a = ar[k];
      An[k*4]   = -__expf(a.x)*LOG2E; An[k*4+1] = -__expf(a.y)*LOG2E;
      An[k*4+2] = -__expf(a.z)*LOG2E; An[k*4+3] = -__expf(a.w)*LOG2E;
    }
  }
  for (int i = 0; i < 4; i++){
    int pix = blockIdx.x*16 + w*4 + i;
    float h[16];
    #pragma unroll
    for (int n = 0; n < 16; n++) h[n] = 0.f;
    #pragma unroll
    for (int l = 0; l < 4; l++){
      int tok = pix*4 + l;
      float pj[36];
      {
        const float4* pr = (const float4*)(proj + (size_t)tok*36);
        #pragma unroll
        for (int k = 0; k < 9; k++){
          float4 v = pr[k];
          pj[k*4]=v.x; pj[k*4+1]=v.y; pj[k*4+2]=v.z; pj[k*4+3]=v.w;
        }
      }
      float xv = xc2[(size_t)tok*64 + lane];
      float zv = zsil2[(size_t)tok*64 + lane];
      float dt = softplusf(dbv + pj[0]*dtwv.x + pj[1]*dtwv.y);
      float ys = 0.f;
      #pragma unroll
      for (int n = 0; n < 16; n++){
        float a = exp2f(dt * An[n]);
        h[n] = a*h[n] + dt * pj[2+n] * xv;
        ys += h[n] * pj[18+n];
      }
      yg[(size_t)tok*64 + lane] = (ys + Dd*xv) * zv;
    }
  }
}

// ---------------- spe D: out-proj GEMM + GN partials -------------------------
__global__ void __launch_bounds__(256)
k_spe_d(const float* __restrict__ yg, const float* __restrict__ out_w,
        float* __restrict__ y2, float* __restrict__ part){
  __shared__ float ldsWT[64*32];
  __shared__ float bst[8];
  int tid = threadIdx.x;
  for (int i = tid; i < 2048; i += 256){
    int c2 = i >> 6, dd = i & 63;
    ldsWT[dd*32 + c2] = out_w[i];
  }
  if (tid < 8) bst[tid] = 0.f;
  __syncthreads();
  int w = tid >> 6, lane = tid & 63;
  int c2 = lane & 31, slot = lane >> 5;
  int tokbase = blockIdx.x*64 + w*16 + slot;
  float acc[8];
  #pragma unroll
  for (int i = 0; i < 8; i++) acc[i] = 0.f;
  for (int dd4 = 0; dd4 < 16; dd4++){
    float w0 = ldsWT[(dd4*4+0)*32 + c2];
    float w1 = ldsWT[(dd4*4+1)*32 + c2];
    float w2 = ldsWT[(dd4*4+2)*32 + c2];
    float w3 = ldsWT[(dd4*4+3)*32 + c2];
    #pragma unroll
    for (int i = 0; i < 8; i++){
      int tok = tokbase + 2*i;
      float4 yv = ((const float4*)(yg + (size_t)tok*64))[dd4];
      acc[i] += yv.x*w0 + yv.y*w1 + yv.z*w2 + yv.w*w3;
    }
  }
  #pragma unroll
  for (int i = 0; i < 8; i++){
    int tok = tokbase + 2*i;
    int pix = tok >> 2, l = tok & 3;
    y2[(size_t)pix*128 + l*32 + c2] = acc[i];
    float s1 = acc[i], s2 = acc[i]*acc[i];
    s1 += __shfl_xor(s1,1);  s2 += __shfl_xor(s2,1);
    s1 += __shfl_xor(s1,2);  s2 += __shfl_xor(s2,2);
    s1 += __shfl_xor(s1,4);  s2 += __shfl_xor(s2,4);
    s1 += __shfl_xor(s1,8);  s2 += __shfl_xor(s2,8);
    s1 += __shfl_xor(s1,16); s2 += __shfl_xor(s2,16);
    if (c2 == 0){
      atomicAdd(&bst[l*2+0], s1);
      atomicAdd(&bst[l*2+1], s2);
    }
  }
  __syncthreads();
  if (tid < 8) part[(size_t)blockIdx.x*8 + tid] = bst[tid];
}

// ---------------- fused fuse + dw: feat in LDS, logits + conv + GN partials --
__global__ void __launch_bounds__(256)
k_fusedw(const float* __restrict__ h1, const float* __restrict__ yproj,
         const float* __restrict__ y2, const float* __restrict__ partSPA,
         const float* __restrict__ partSPE,
         const float* __restrict__ spa_g, const float* __restrict__ spa_b,
         const float* __restrict__ spe_g, const float* __restrict__ spe_b,
         const float* __restrict__ fuse_w, const float* __restrict__ cls_w,
         const float* __restrict__ cls_b, const float* __restrict__ dww,
         float* __restrict__ logits, float* __restrict__ epre,
         float* __restrict__ part){
  __shared__ float ft[60*129];
  __shared__ float clsL[10*129];
  __shared__ float sst[32];
  __shared__ float red1[4][64], red2[4][64];
  int tid = threadIdx.x;
  reduce_part(partSPA, 256, sst);
  reduce_part(partSPE, 256, sst+16);
  for (int i = tid; i < 1280; i += 256){
    int o = i >> 7, cc = i & 127;
    clsL[o*129 + cc] = cls_w[o*128 + cc];
  }
  int blk = blockIdx.x;
  int b = blk >> 7, rem = blk & 127;
  int ty = rem >> 3, tx = rem & 7;
  int r0 = ty*4, c0 = tx*8;
  float e0 = __expf(fuse_w[0]), e1 = __expf(fuse_w[1]);
  float wA = e0/(e0+e1), wB = e1/(e0+e1);
  for (int idx = tid; idx < 7680; idx += 256){
    int pos = idx >> 7, c = idx & 127;
    int hr = pos/10, hc = pos - hr*10;
    int ry = r0 + hr - 1, rx = c0 + hc - 1;
    float f = 0.f;
    if (ry >= 0 && ry < 64 && rx >= 0 && rx < 64){
      size_t pix = (size_t)((b<<12)|(ry<<6)|rx);
      int g = c >> 5;
      float m1 = sst[b*8 + g*2]      * (1.f/NG);
      float v1 = sst[b*8 + g*2 + 1]  * (1.f/NG) - m1*m1;
      float m2 = sst[16 + b*8 + g*2] * (1.f/NG);
      float v2 = sst[16 + b*8 + g*2+1]*(1.f/NG) - m2*m2;
      float h = h1[pix*128 + c];
      float sa = siluf((yproj[pix*128+c]-m1)*rsqrtf(v1+1e-5f)*spa_g[c] + spa_b[c]) + h;
      float sp = h + siluf((y2[pix*128+c]-m2)*rsqrtf(v2+1e-5f)*spe_g[c] + spe_b[c]);
      f = sa*wA + sp*wB + h;
    }
    ft[pos*129 + c] = f;
  }
  __syncthreads();
  int c = tid & 127, pl = tid >> 7;
  float w9[9];
  #pragma unroll
  for (int k = 0; k < 9; k++) w9[k] = dww[c*9+k];
  float s1 = 0.f, s2 = 0.f;
  for (int i = 0; i < 16; i++){
    int px = i*2 + pl;
    int py = px >> 3, pxx = px & 7;
    float acc = 0.f;
    #pragma unroll
    for (int dy = 0; dy < 3; dy++)
      #pragma unroll
      for (int dx = 0; dx < 3; dx++)
        acc += ft[((py+dy)*10 + (pxx+dx))*129 + c] * w9[dy*3+dx];
    epre[(size_t)((b<<12)|((r0+py)<<6)|(c0+pxx))*128 + c] = acc;
    s1 += acc; s2 += acc*acc;
  }
  for (int idx = tid; idx < 320; idx += 256){
    int px = idx/10, o = idx - px*10;
    int py = px >> 3, pxx = px & 7;
    int pos = (py+1)*10 + (pxx+1);
    float acc = cls_b[o];
    for (int cc = 0; cc < 128; cc++)
      acc += ft[pos*129 + cc] * clsL[o*129 + cc];
    logits[(size_t)((b<<12)|((r0+py)<<6)|(c0+pxx))*16 + o] = acc;
  }
  int g = c >> 5;
  int ridx0 = (c & 31) | (pl << 5);
  red1[g][ridx0] = s1; red2[g][ridx0] = s2;
  __syncthreads();
  int rg = tid >> 6, ridx = tid & 63;
  for (int s = 32; s >= 1; s >>= 1){
    if (ridx < s){ red1[rg][ridx] += red1[rg][ridx+s]; red2[rg][ridx] += red2[rg][ridx+s]; }
    __syncthreads();
  }
  if (ridx == 0){
    part[(size_t)blk*8 + rg*2+0] = red1[rg][0];
    part[(size_t)blk*8 + rg*2+1] = red2[rg][0];
  }
}

// ---------------- final: inline ref-stats reduce + edge + local avg ----------
__global__ void __launch_bounds__(256)
k_final(const float* __restrict__ epre, const float* __restrict__ logits,
        const float* __restrict__ partDW, const float* __restrict__ rg_g,
        const float* __restrict__ rg_b, const float* __restrict__ pw_w,
        const float* __restrict__ pw_b, const float* __restrict__ alpha,
        float* __restrict__ outp){
  __shared__ float sst[16];
  __shared__ float part[4];
  __shared__ float edge_s[2];
  reduce_part(partDW, 128, sst);
  int tid = threadIdx.x;
  int pixl = tid >> 7, c = tid & 127;
  int pix = blockIdx.x*2 + pixl;
  int b = pix >> 12, p = pix & 4095, yy = p >> 6, xx = p & 63;
  int g = c >> 5;
  float m = sst[b*8 + g*2]   * (1.f/NG);
  float v = sst[b*8 + g*2+1] * (1.f/NG) - m*m;
  float e = epre[(size_t)pix*128+c];
  float en = siluf((e-m)*rsqrtf(v+1e-5f)*rg_g[c] + rg_b[c]);
  float pv = en * pw_w[c];
  pv += __shfl_xor(pv,1);  pv += __shfl_xor(pv,2);  pv += __shfl_xor(pv,4);
  pv += __shfl_xor(pv,8);  pv += __shfl_xor(pv,16); pv += __shfl_xor(pv,32);
  if ((tid & 63) == 0) part[tid>>6] = pv;
  __syncthreads();
  if (tid < 2) edge_s[tid] = sigm(part[tid*2] + part[tid*2+1] + pw_b[0]);
  __syncthreads();
  if (c < 10){
    float ed = edge_s[pixl];
    int o = c;
    float lg = logits[(size_t)pix*16 + o];
    float loc = 0.f;
    for (int dy = -1; dy <= 1; dy++){
      int ny = yy+dy; if (ny < 0 || ny > 63) continue;
      for (int dx = -1; dx <= 1; dx++){
        int nx = xx+dx; if (nx < 0 || nx > 63) continue;
        loc += logits[(size_t)((b<<12)|(ny<<6)|nx)*16 + o];
      }
    }
    loc *= (1.f/9.f);
    outp[(size_t)((b*10+o)<<12) + p] = lg + alpha[0]*(1.f-ed)*(loc - lg);
  }
}

extern "C" void kernel_launch(void* const* d_in, const int* in_sizes, int n_in,
                              void* d_out, int out_size, void* d_ws, size_t ws_size,
                              hipStream_t stream){
  const float* x          = (const float*)d_in[0];
  const float* pe_w       = (const float*)d_in[1];
  const float* pe_b       = (const float*)d_in[2];
  const float* pe_gn_g    = (const float*)d_in[3];
  const float* pe_gn_b    = (const float*)d_in[4];
  const float* spa_in_w   = (const float*)d_in[5];
  const float* spa_conv_w = (const float*)d_in[6];
  const float* spa_conv_b = (const float*)d_in[7];
  const float* spa_xproj_w= (const float*)d_in[8];
  const float* spa_dt_w   = (const float*)d_in[9];
  const float* spa_dt_b   = (const float*)d_in[10];
  const float* spa_Alog   = (const float*)d_in[11];
  const float* spa_D      = (const float*)d_in[12];
  const float* spa_out_w  = (const float*)d_in[13];
  const float* spa_gn_g   = (const float*)d_in[14];
  const float* spa_gn_b   = (const float*)d_in[15];
  const float* spe_in_w   = (const float*)d_in[16];
  const float* spe_conv_w = (const float*)d_in[17];
  const float* spe_conv_b = (const float*)d_in[18];
  const float* spe_xproj_w= (const float*)d_in[19];
  const float* spe_dt_w   = (const float*)d_in[20];
  const float* spe_dt_b   = (const float*)d_in[21];
  const float* spe_Alog   = (const float*)d_in[22];
  const float* spe_D      = (const float*)d_in[23];
  const float* spe_out_w  = (const float*)d_in[24];
  const float* spe_gn_g   = (const float*)d_in[25];
  const float* spe_gn_b   = (const float*)d_in[26];
  const float* fuse_w     = (const float*)d_in[27];
  const float* cls_w      = (const float*)d_in[28];
  const float* cls_b      = (const float*)d_in[29];
  const float* ref_dw_w   = (const float*)d_in[30];
  const float* ref_gn_g   = (const float*)d_in[31];
  const float* ref_gn_b   = (const float*)d_in[32];
  const float* ref_pw_w   = (const float*)d_in[33];
  const float* ref_pw_b   = (const float*)d_in[34];
  const float* alpha      = (const float*)d_in[35];
  float* ws  = (float*)d_ws;
  float* out = (float*)d_out;

  float* Pb    = ws + WS_POFF;   // hs aliases Pb (scan2 in-place)
  float* Qb    = ws + WS_QOFF;   // Q dead after scan2 (proj2/logits written later)
  float* HSb   = Pb;
  float* dely  = ws + WS_Y;      // delta; scan3 writes y over it
  float* partPE  = ws + WS_Y;          // consumed by k_xz before k_projc overwrites
  float* partSPA = ws + WS_POFF;       // hs dead after scan3
  float* partSPE = ws + WS_POFF + 16384;
  float* partDW  = ws + WS_POFF + 65536;
  float* proj  = ws + WS_PROJ;
  float* xc2   = ws + WS_XC;           // xc dead after scan3
  float* zsil2 = ws + WS_XZD;          // xzd dead after projc
  float* proj2 = ws + WS_QOFF;         // Q dead after scan2
  float* yg    = ws + WS_Y;            // y dead after outproj
  float* epre  = ws + WS_Y;            // yg dead after spe_d... epre written by fusedw

  k_pe<<<dim3(2,256),256,0,stream>>>(x, pe_w, pe_b, ws+WS_H1PRE, partPE);
  k_xz<<<dim3(8,128),256,0,stream>>>(ws+WS_H1PRE, spa_in_w, partPE,
      pe_gn_g, pe_gn_b, ws+WS_H1, ws+WS_XZD, ws+WS_ZSIL);
  k_projc<<<512,256,0,stream>>>(ws+WS_XZD, spa_conv_w, spa_conv_b, spa_xproj_w,
      spa_dt_w, spa_dt_b, ws+WS_XC, proj, dely);
  k_scan1<<<2048,256,0,stream>>>(dely, proj, ws+WS_XC, spa_Alog, Pb, Qb);
  k_scan2<<<512,256,0,stream>>>(Pb, Qb, HSb);
  k_scan3<<<2048,256,0,stream>>>(dely, proj, ws+WS_XC, ws+WS_ZSIL,
      spa_Alog, spa_D, HSb, dely);
  k_outproj<<<dim3(2,256),256,0,stream>>>(dely, spa_out_w, ws+WS_H1PRE, partSPA);
  k_spe_ab<<<512,256,0,stream>>>(ws+WS_H1, spe_in_w, spe_conv_w, spe_conv_b,
      spe_xproj_w, xc2, zsil2, proj2);
  k_spe_c<<<512,256,0,stream>>>(xc2, zsil2, proj2, spe_dt_w, spe_dt_b,
      spe_Alog, spe_D, yg);
  k_spe_d<<<512,256,0,stream>>>(yg, spe_out_w, ws+WS_Y2, partSPE);
  k_fusedw<<<256,256,0,stream>>>(ws+WS_H1, ws+WS_H1PRE, ws+WS_Y2,
      partSPA, partSPE, spa_gn_g, spa_gn_b, spe_gn_g, spe_gn_b,
      fuse_w, cls_w, cls_b, ref_dw_w, ws+WS_LOG, epre, partDW);
  k_final<<<4096,256,0,stream>>>(epre, ws+WS_LOG, partDW,
      ref_gn_g, ref_gn_b, ref_pw_w, ref_pw_b, alpha, out);
  (void)in_sizes; (void)n_in; (void)out_size; (void)ws_size;
}